// Round 1
// 1525.883 us; speedup vs baseline: 2.6798x; 2.6798x over previous
//
#include <hip/hip_runtime.h>
#include <math.h>

#define A_NUM 9
#define NCLS 80
#define IMG_KEY 3916800   // 720*5440
#define IMG_REG 195840    // 36*5440
#define CAP 8192
#define HBINS 16384

// ---- f16 hi/lo split activation & weight layouts --------------------------
// Activations per (img[,head]), per ci16-chunk, per level:
//   slot(16B) = lvlSlot + ((row*2+plane)*2+half)*C + col,  slot holds 8 f16 (ci8)
//   plane: 0=hi, 1=lo ; half: ci bit3 ; row/col padded (+1 halo)
// Levels: L0 66x66, L1 34x34, L2 18x18, L3 10x18 (cols 10..17 stay zero)
#define CHUNK_SLOTS 24064                       // 17424+4624+1296+720
#define CHUNK_BYTES (CHUNK_SLOTS * 16)          // 385024
#define ACT_SLAB ((size_t)CHUNK_BYTES * 16)     // 6160384 B per (img,head)
// Weights per co-group(64), per chunk: [kstep5][tap2][plane2][half2][co64][ci8]
#define WCHUNK_BYTES 40960
#define WCOG_BYTES (WCHUNK_BYTES * 16)          // 655360

typedef _Float16 h8 __attribute__((ext_vector_type(8)));
typedef float fx4 __attribute__((ext_vector_type(4)));
typedef unsigned short u16;

__constant__ int   c_W[4]       = {64, 32, 16, 8};
__constant__ int   c_stride[4]  = {8, 16, 32, 64};
__constant__ float c_sizes[4][3]= {{32.f,40.f,50.f},{64.f,80.f,101.f},{128.f,161.f,203.f},{256.f,322.f,406.f}};
__constant__ int   c_keyOff[4]  = {0, 2949120, 3686400, 3870720};
__constant__ int   c_keyCnt[4]  = {2949120, 737280, 184320, 46080};
__constant__ int   c_regOff[4]  = {0, 147456, 184320, 193536};
__constant__ int   c_C[4]       = {66, 34, 18, 18};
__constant__ int   c_lvlSlot[4] = {0, 17424, 22048, 23344};
__constant__ int   c_pOff[4]    = {0, 1024, 1280, 1344};

// global_load_lds, 16B/lane: LDS dest = wave-uniform base + lane*16.
__device__ __forceinline__ void gl_lds16(const void* g, void* l) {
    __builtin_amdgcn_global_load_lds(
        (const __attribute__((address_space(1))) void*)g,
        (__attribute__((address_space(3))) void*)l, 16, 0, 0);
}

// ---------------------------------------------------------------------------
// prep: pad f0..f3 (fp32) into Pin in f16 hi/lo split layout (interior only;
// halo stays zero from memset). One thread: 8 ci x 4 cols for one (chunk,half).
// ---------------------------------------------------------------------------
__global__ __launch_bounds__(256) void pad16_k(
    const float* __restrict__ f0, const float* __restrict__ f1,
    const float* __restrict__ f2, const float* __restrict__ f3,
    char* __restrict__ Pin)
{
    int idx = blockIdx.x * 256 + threadIdx.x;
    const int PER_IMG = 16 * 2 * 1360;
    if (idx >= 4 * PER_IMG) return;
    int img = idx / PER_IMG;
    int r = idx - img * PER_IMG;
    int chunk = r / (2 * 1360);
    int r2 = r - chunk * (2 * 1360);
    int hfsel = r2 / 1360;
    int p = r2 - hfsel * 1360;
    int lvl = (p < 1024) ? 0 : (p < 1280 ? 1 : (p < 1344 ? 2 : 3));
    int u = p - c_pOff[lvl];
    int sh = 4 - lvl;
    int y = u >> sh;
    int xg = u & ((1 << sh) - 1);
    int x0 = xg * 4;
    int W = 64 >> lvl;
    const float* f = (lvl == 0) ? f0 : (lvl == 1) ? f1 : (lvl == 2) ? f2 : f3;
    int ci0 = chunk * 16 + hfsel * 8;
    float4 v[8];
    #pragma unroll
    for (int j = 0; j < 8; ++j)
        v[j] = *reinterpret_cast<const float4*>(
            f + ((size_t)(img * 256 + ci0 + j)) * (W * W) + y * W + x0);
    char* base = Pin + (size_t)img * ACT_SLAB + (size_t)chunk * CHUNK_BYTES;
    const int C = c_C[lvl];
    size_t rowSlot = (size_t)c_lvlSlot[lvl] + (size_t)((y + 1) * 4 + hfsel) * C;
    #pragma unroll
    for (int c = 0; c < 4; ++c) {
        h8 hv, lv;
        #pragma unroll
        for (int j = 0; j < 8; ++j) {
            float val = (c == 0) ? v[j].x : (c == 1) ? v[j].y : (c == 2) ? v[j].z : v[j].w;
            _Float16 hh = (_Float16)val;
            hv[j] = hh;
            lv[j] = (_Float16)(val - (float)hh);
        }
        size_t slot = rowSlot + (x0 + c + 1);
        *reinterpret_cast<h8*>(base + slot * 16) = hv;                       // hi plane
        *reinterpret_cast<h8*>(base + (slot + 2 * (size_t)C) * 16) = lv;     // lo plane
    }
}

// ---------------------------------------------------------------------------
// prep: repack conv weights fp32 [L][C_out][256][3][3] ->
// per (layer,cg,chunk): [kstep5][tap2][plane2][half2][co64][ci8] f16, kk==9 zero.
// One thread: one (kk,half,co) -> 8 ci, writes hi 16B + lo 16B.
// ---------------------------------------------------------------------------
__global__ __launch_bounds__(256) void repack16_k(
    const float* __restrict__ src, u16* __restrict__ dst,
    int C_out, int nCg, int total)
{
    int idx = blockIdx.x * 256 + threadIdx.x;
    if (idx >= total) return;
    int per = nCg * 16 * 1280;
    int layer = idx / per;
    int r = idx - layer * per;
    int cg = r / (16 * 1280);
    int r2 = r - cg * (16 * 1280);
    int chunk = r2 / 1280;
    int s = r2 - chunk * 1280;
    int co = s & 63;
    int r3 = s >> 6;
    int hfsel = r3 & 1;
    int kk = r3 >> 1;                 // 0..9 ; 9 = zero-pad tap
    int coG = cg * 64 + co;
    float v[8];
    if (kk < 9 && coG < C_out) {
        const float* sp = src + ((size_t)(layer * C_out + coG)) * 2304
                        + (size_t)(chunk * 16 + hfsel * 8) * 9 + kk;
        #pragma unroll
        for (int j = 0; j < 8; ++j) v[j] = sp[j * 9];
    } else {
        #pragma unroll
        for (int j = 0; j < 8; ++j) v[j] = 0.f;
    }
    h8 hv, lv;
    #pragma unroll
    for (int j = 0; j < 8; ++j) {
        _Float16 hh = (_Float16)v[j];
        hv[j] = hh;
        lv[j] = (_Float16)(v[j] - (float)hh);
    }
    size_t e = ((size_t)((layer * nCg + cg) * 16 + chunk)) * 20480
             + (size_t)(kk >> 1) * 4096 + (size_t)(kk & 1) * 2048
             + (size_t)hfsel * 512 + (size_t)co * 8;
    *reinterpret_cast<h8*>(dst + e) = hv;             // plane 0 (hi)
    *reinterpret_cast<h8*>(dst + e + 1024) = lv;      // plane 1 (lo)
}

// ---------------------------------------------------------------------------
// Fused 3x3 SAME conv via MFMA f16 hi/lo split (3 mfma: hh + hl + lh), fp32 acc.
// Block: 8 rows x 16 cols x 64 co. Wave: 2 row-tiles(M=16 px) x 4 co-tiles(N=16).
// K-loop: 16 chunks of 16 ci; per chunk 5 K-steps of (2 taps x 16 ci), tap 9 = zero.
// A frag: lane m=l&15 (px col), kgrp g=l>>4 -> (tap=g>>1, half=g&1), 8 ci b128.
// B frag: lane n=l&15 (co), same kgrp mapping. Both LDS reads conflict-free
// (16 consecutive lanes read 16 contiguous 16B slots).
// ---------------------------------------------------------------------------
__global__ __launch_bounds__(256, 3) void conv16(
    const char* __restrict__ Pin, const char* __restrict__ bufIn, char* __restrict__ bufOut,
    const u16* __restrict__ repA, const float* __restrict__ bA,
    const u16* __restrict__ repB, const float* __restrict__ bB,
    unsigned* __restrict__ keys, float* __restrict__ regb,
    int mode, int usePin)
{
    const int tid = threadIdx.x;
    const int lane = tid & 63;
    const int wv = tid >> 6;
    const int t43 = blockIdx.x;

    int img, head, coBase, C_out, epi;
    if (mode == 0) {
        img = blockIdx.z & 3; head = blockIdx.z >> 2;
        coBase = blockIdx.y * 64; C_out = 256; epi = 0;
    } else {
        img = blockIdx.z;
        if (blockIdx.y < 12) { head = 0; coBase = blockIdx.y * 64; C_out = 720; epi = 1; }
        else                 { head = 1; coBase = 0;               C_out = 36;  epi = 2; }
    }
    const float* bsel = head ? bB : bA;
    const u16* wsel = head ? repB : repA;
    const char* wBase = (const char*)wsel + (size_t)(coBase >> 6) * WCOG_BYTES;

    int lvl, ty, tx;
    if (t43 < 32)      { lvl = 0; ty = t43 >> 2; tx = t43 & 3; }
    else if (t43 < 40) { int u = t43 - 32; lvl = 1; ty = u >> 1; tx = u & 1; }
    else if (t43 < 42) { lvl = 2; ty = t43 - 40; tx = 0; }
    else               { lvl = 3; ty = 0; tx = 0; }
    const int W = 64 >> lvl;
    const int C = c_C[lvl];
    const int tileY = ty * 8, tileX = tx * 16;

    const char* srcB = usePin ? Pin + (size_t)img * ACT_SLAB
                              : bufIn + (size_t)(head * 4 + img) * ACT_SLAB;

    __shared__ alignas(16) char sA[11520];   // [row10][plane2][half2][col18][ci8]
    __shared__ alignas(16) char sB[40960];   // [kstep5][tap2][plane2][half2][co64][ci8]

    const int laneCol = lane & 15;
    const int g = lane >> 4;
    const int halfS = g & 1;
    const int tapS = g >> 1;
    int laneA[5];
    #pragma unroll
    for (int k = 0; k < 5; ++k) {
        int kk = 2 * k + tapS; if (kk > 8) kk = 8;   // kk==9 pairs with zero B
        int ky = kk / 3;
        int kx = kk - ky * 3;
        laneA[k] = ky * 1152 + halfS * 288 + (laneCol + kx) * 16;
    }
    const int laneB = tapS * 4096 + halfS * 1024 + laneCol * 16;

    // A staging tables: 720 slots of 16B, 3 per thread
    size_t aSrc[3]; int aDst[3]; bool aOk[3];
    #pragma unroll
    for (int p = 0; p < 3; ++p) {
        int s = tid + 256 * p;
        aOk[p] = (s < 720);
        int sc = aOk[p] ? s : 719;
        int row = sc / 72;
        int q = sc - row * 72;
        int pl = q / 36;
        int q2 = q - pl * 36;
        int hf = q2 / 18;
        int col = q2 - hf * 18;
        aSrc[p] = (size_t)(c_lvlSlot[lvl] + ((tileY + row) * 4 + pl * 2 + hf) * C
                           + tileX + col) * 16;
        aDst[p] = sc * 16;
    }

    fx4 acc[2][4];
    #pragma unroll
    for (int mt = 0; mt < 2; ++mt)
        #pragma unroll
        for (int nt = 0; nt < 4; ++nt)
            acc[mt][nt] = (fx4){0.f, 0.f, 0.f, 0.f};

    #pragma unroll 1
    for (int ck = 0; ck < 16; ++ck) {
        int4 av[3];
        const char* srcCk = srcB + (size_t)ck * CHUNK_BYTES;
        #pragma unroll
        for (int p = 0; p < 3; ++p)
            if (aOk[p]) av[p] = *reinterpret_cast<const int4*>(srcCk + aSrc[p]);
        const char* wCk = wBase + (size_t)ck * WCHUNK_BYTES;
        for (int j = wv; j < 40; j += 4)
            gl_lds16(wCk + j * 1024 + lane * 16, (char*)sB + j * 1024);
        #pragma unroll
        for (int p = 0; p < 3; ++p)
            if (aOk[p]) *reinterpret_cast<int4*>(sA + aDst[p]) = av[p];
        __syncthreads();   // drains vmcnt+lgkm -> LDS ready

        #pragma unroll
        for (int k = 0; k < 5; ++k) {
            const char* bk = sB + k * 8192;
            h8 Bh[4], Bl[4];
            #pragma unroll
            for (int nt = 0; nt < 4; ++nt) {
                Bh[nt] = *reinterpret_cast<const h8*>(bk + nt * 256 + laneB);
                Bl[nt] = *reinterpret_cast<const h8*>(bk + 2048 + nt * 256 + laneB);
            }
            #pragma unroll
            for (int mt = 0; mt < 2; ++mt) {
                const char* am = sA + (wv * 2 + mt) * 1152 + laneA[k];
                h8 Ah = *reinterpret_cast<const h8*>(am);
                h8 Al = *reinterpret_cast<const h8*>(am + 576);
                #pragma unroll
                for (int nt = 0; nt < 4; ++nt) {
                    acc[mt][nt] = __builtin_amdgcn_mfma_f32_16x16x32_f16(Ah, Bh[nt], acc[mt][nt], 0, 0, 0);
                    acc[mt][nt] = __builtin_amdgcn_mfma_f32_16x16x32_f16(Ah, Bl[nt], acc[mt][nt], 0, 0, 0);
                    acc[mt][nt] = __builtin_amdgcn_mfma_f32_16x16x32_f16(Al, Bh[nt], acc[mt][nt], 0, 0, 0);
                }
            }
        }
        __syncthreads();
    }

    // ---- epilogue: C frag col(n)=lane&15 (co), row(m)=(lane>>4)*4+i (4 consec px)
    const int HW = W * W;
    if (epi == 0) {
        char* dstB = bufOut + (size_t)(head * 4 + img) * ACT_SLAB;
        #pragma unroll
        for (int mt = 0; mt < 2; ++mt) {
            int y = tileY + wv * 2 + mt;
            int gy4 = (y + 1) * 4;
            #pragma unroll
            for (int nt = 0; nt < 4; ++nt) {
                int coG = coBase + nt * 16 + laneCol;
                float b = bsel[coG];
                size_t sBase = (size_t)(coG >> 4) * CHUNK_SLOTS + c_lvlSlot[lvl]
                             + (size_t)(gy4 + ((coG >> 3) & 1)) * C;
                int ci8 = coG & 7;
                #pragma unroll
                for (int i = 0; i < 4; ++i) {
                    int x = tileX + g * 4 + i;
                    if (x >= W) continue;        // lvl3 garbage half
                    float v = fmaxf(acc[mt][nt][i] + b, 0.f);
                    _Float16 hh = (_Float16)v;
                    _Float16 ll = (_Float16)(v - (float)hh);
                    size_t slot = sBase + (x + 1);
                    *reinterpret_cast<_Float16*>(dstB + slot * 16 + ci8 * 2) = hh;
                    *reinterpret_cast<_Float16*>(dstB + (slot + 2 * (size_t)C) * 16 + ci8 * 2) = ll;
                }
            }
        }
    } else if (epi == 1) {
        unsigned* kb = keys + (size_t)img * IMG_KEY + c_keyOff[lvl];
        #pragma unroll
        for (int mt = 0; mt < 2; ++mt) {
            int y = tileY + wv * 2 + mt;
            int x0 = tileX + g * 4;
            if (x0 >= W) continue;               // lvl3 garbage half
            #pragma unroll
            for (int nt = 0; nt < 4; ++nt) {
                int coG = coBase + nt * 16 + laneCol;
                if (coG >= C_out) continue;
                float b = bsel[coG];
                unsigned kq[4];
                #pragma unroll
                for (int i = 0; i < 4; ++i) {
                    float sc = 1.0f / (1.0f + expf(-(acc[mt][nt][i] + b)));
                    kq[i] = (sc > 0.05f) ? __float_as_uint(sc) : 0u;
                }
                *reinterpret_cast<uint4*>(kb + (size_t)coG * HW + y * W + x0) =
                    make_uint4(kq[0], kq[1], kq[2], kq[3]);
            }
        }
    } else {
        float* rb = regb + (size_t)img * IMG_REG + c_regOff[lvl];
        #pragma unroll
        for (int mt = 0; mt < 2; ++mt) {
            int y = tileY + wv * 2 + mt;
            #pragma unroll
            for (int nt = 0; nt < 4; ++nt) {
                int coG = nt * 16 + laneCol;
                if (coG >= C_out) continue;
                float b = bsel[coG];
                int a = coG >> 2, jj = coG & 3;
                #pragma unroll
                for (int i = 0; i < 4; ++i) {
                    int x = tileX + g * 4 + i;
                    if (x >= W) continue;
                    rb[((size_t)(y * W + x) * A_NUM + a) * 4 + jj] = acc[mt][nt][i] + b;
                }
            }
        }
    }
}

// ---------------------------------------------------------------------------
__global__ __launch_bounds__(256) void hist_k(const unsigned* __restrict__ keys,
                                              unsigned* __restrict__ hist)
{
    int il = blockIdx.y, img = il >> 2, lvl = il & 3;
    int n = c_keyCnt[lvl];
    int chunk = blockIdx.x * 16384;
    if (chunk >= n) return;
    __shared__ unsigned h[HBINS];
    for (int t = threadIdx.x; t < HBINS; t += 256) h[t] = 0;
    __syncthreads();
    const uint4* k4 = (const uint4*)(keys + (size_t)img * IMG_KEY + c_keyOff[lvl]);
    int i0 = chunk >> 2, i1 = min(chunk + 16384, n) >> 2;
    for (int i = i0 + (int)threadIdx.x; i < i1; i += 256) {
        uint4 kv = k4[i];
        if (kv.x) atomicAdd(&h[kv.x >> 18], 1u);
        if (kv.y) atomicAdd(&h[kv.y >> 18], 1u);
        if (kv.z) atomicAdd(&h[kv.z >> 18], 1u);
        if (kv.w) atomicAdd(&h[kv.w >> 18], 1u);
    }
    __syncthreads();
    unsigned* gh = hist + (size_t)il * HBINS;
    for (int t = threadIdx.x; t < HBINS; t += 256)
        if (h[t]) atomicAdd(&gh[t], h[t]);
}

__global__ __launch_bounds__(256) void thresh_k(const unsigned* __restrict__ hist,
                                                unsigned* __restrict__ tbin)
{
    const unsigned* h = hist + (size_t)blockIdx.x * HBINS;
    __shared__ unsigned cs[256];
    int tid = threadIdx.x;
    unsigned s = 0;
    int base = tid * 64;
    for (int q = 0; q < 64; ++q) { int b = base + q; if (b >= 1) s += h[b]; }
    cs[tid] = s;
    __syncthreads();
    if (tid == 0) {
        unsigned total = 0, sel = 0;
        for (int c = 255; c >= 0; --c) {
            if (total + cs[c] >= 100u) {
                int lo = (c == 0) ? 1 : c * 64;
                for (int b = c * 64 + 63; b >= lo; --b) {
                    total += h[b];
                    if (total >= 100u) { sel = (unsigned)b; break; }
                }
                break;
            }
            total += cs[c];
        }
        tbin[blockIdx.x] = sel;
    }
}

__global__ __launch_bounds__(256) void compact_k(const unsigned* __restrict__ keys,
                                                 const unsigned* __restrict__ tbin,
                                                 unsigned* __restrict__ cnt,
                                                 uint2* __restrict__ comp)
{
    int il = blockIdx.y, img = il >> 2, lvl = il & 3;
    int n = c_keyCnt[lvl];
    int chunk = blockIdx.x * 16384;
    if (chunk >= n) return;
    const uint4* k4 = (const uint4*)(keys + (size_t)img * IMG_KEY + c_keyOff[lvl]);
    unsigned thr = tbin[il] << 18;
    int shift = 12 - 2 * lvl;
    int hwm = (1 << shift) - 1;
    int i0 = chunk >> 2, i1 = min(chunk + 16384, n) >> 2;
    __shared__ unsigned lcnt, lbase, lcur;
    if (threadIdx.x == 0) { lcnt = 0; lcur = 0; }
    __syncthreads();
    unsigned myc = 0;
    for (int i = i0 + (int)threadIdx.x; i < i1; i += 256) {
        uint4 kv = k4[i];
        myc += (kv.x != 0u && kv.x >= thr);
        myc += (kv.y != 0u && kv.y >= thr);
        myc += (kv.z != 0u && kv.z >= thr);
        myc += (kv.w != 0u && kv.w >= thr);
    }
    if (myc) atomicAdd(&lcnt, myc);
    __syncthreads();
    if (threadIdx.x == 0 && lcnt) lbase = atomicAdd(&cnt[il], lcnt);
    __syncthreads();
    if (lcnt == 0) return;
    uint2* c = comp + (size_t)il * CAP;
    for (int i = i0 + (int)threadIdx.x; i < i1; i += 256) {
        uint4 kv = k4[i];
        unsigned kk[4] = {kv.x, kv.y, kv.z, kv.w};
        #pragma unroll
        for (int j = 0; j < 4; ++j) {
            unsigned key = kk[j];
            if (key != 0u && key >= thr) {
                int t = i * 4 + j;
                int co = t >> shift, p = t & hwm;
                int a = co / NCLS, cls = co - a * NCLS;
                unsigned idx = (unsigned)((p * A_NUM + a) * NCLS + cls);
                unsigned pos = lbase + atomicAdd(&lcur, 1u);
                if (pos < CAP) c[pos] = make_uint2(key, idx);
            }
        }
    }
}

__global__ __launch_bounds__(256) void topsort_k(const unsigned* __restrict__ cnt,
                                                 const uint2* __restrict__ comp,
                                                 uint2* __restrict__ topk)
{
    __shared__ unsigned long long s[CAP];
    int il = blockIdx.x, tid = threadIdx.x;
    int n = (int)min(cnt[il], (unsigned)CAP);
    const uint2* c = comp + (size_t)il * CAP;
    for (int i = tid; i < CAP; i += 256) {
        unsigned long long v = 0ull;
        if (i < n) {
            uint2 e = c[i];
            v = ((unsigned long long)e.x << 32) | (unsigned long long)(~e.y);
        }
        s[i] = v;
    }
    for (int k = 2; k <= CAP; k <<= 1) {
        for (int j = k >> 1; j > 0; j >>= 1) {
            __syncthreads();
            for (int p = tid; p < CAP / 2; p += 256) {
                int i = ((p & ~(j - 1)) << 1) | (p & (j - 1));
                int ixj = i | j;
                unsigned long long a = s[i], b = s[ixj];
                if (((i & k) == 0) ? (a < b) : (a > b)) { s[i] = b; s[ixj] = a; }
            }
        }
    }
    __syncthreads();
    if (tid < 100) {
        unsigned long long v = s[tid];
        topk[il * 100 + tid] = make_uint2((unsigned)(v >> 32), ~(unsigned)(v & 0xFFFFFFFFull));
    }
}

// ---------------------------------------------------------------------------
__global__ void decode_k(const uint2* __restrict__ topk, const float* __restrict__ regb,
                         float* __restrict__ cboxes, float* __restrict__ cscores,
                         int* __restrict__ clabels, const int* __restrict__ ph, const int* __restrict__ pw)
{
    int il = blockIdx.x, img = il >> 2, lvl = il & 3;
    int j = threadIdx.x;
    if (j >= 100) return;
    float imgW = (float)pw[0], imgH = (float)ph[0];
    uint2 tk = topk[il * 100 + j];
    int outP = img * 400 + lvl * 100 + j;
    if (tk.x == 0u) {
        cboxes[outP * 4 + 0] = 0.f; cboxes[outP * 4 + 1] = 0.f;
        cboxes[outP * 4 + 2] = 0.f; cboxes[outP * 4 + 3] = 0.f;
        cscores[outP] = -1.0f; clabels[outP] = -1;
        return;
    }
    float score = __uint_as_float(tk.x);
    unsigned idx = tk.y;
    int aidx = (int)(idx / NCLS);
    int lbl  = (int)(idx - (unsigned)aidx * NCLS);
    int a = aidx % A_NUM, p = aidx / A_NUM;
    int W = c_W[lvl];
    int y = p / W, x = p - y * W;
    int r = a / 3, si = a - r * 3;
    float ratio = (r == 0) ? 0.5f : ((r == 1) ? 1.0f : 2.0f);
    float size = c_sizes[lvl][si];
    float hr = sqrtf(ratio);
    float wr = 1.0f / hr;
    float wsz = wr * size, hsz = hr * size;
    float bw = rintf(wsz * 0.5f), bh = rintf(hsz * 0.5f);
    float sx = (float)(x * c_stride[lvl]), sy = (float)(y * c_stride[lvl]);
    float ax1 = fminf(fmaxf(sx - bw, 0.f), imgW);
    float ay1 = fminf(fmaxf(sy - bh, 0.f), imgH);
    float ax2 = fminf(fmaxf(sx + bw, 0.f), imgW);
    float ay2 = fminf(fmaxf(sy + bh, 0.f), imgH);
    float aw = ax2 - ax1, ah = ay2 - ay1;
    float cx = ax1 + 0.5f * aw, cy = ay1 + 0.5f * ah;
    const float* rel = regb + (size_t)img * IMG_REG + c_regOff[lvl] + (size_t)aidx * 4;
    float dx = rel[0], dy = rel[1];
    float dw = fminf(rel[2], 4.135166556742356f);
    float dh = fminf(rel[3], 4.135166556742356f);
    float pcx = dx * aw + cx, pcy = dy * ah + cy;
    float pwd = expf(dw) * aw, phd = expf(dh) * ah;
    float x1 = pcx - 0.5f * pwd, y1 = pcy - 0.5f * phd;
    float x2 = pcx + 0.5f * pwd, y2 = pcy + 0.5f * phd;
    cboxes[outP * 4 + 0] = fminf(fmaxf(x1, 0.f), imgW);
    cboxes[outP * 4 + 1] = fminf(fmaxf(y1, 0.f), imgH);
    cboxes[outP * 4 + 2] = fminf(fmaxf(x2, 0.f), imgW);
    cboxes[outP * 4 + 3] = fminf(fmaxf(y2, 0.f), imgH);
    cscores[outP] = score;
    clabels[outP] = lbl;
}

__global__ __launch_bounds__(512) void nms_k(const float* __restrict__ cboxes,
                                             const float* __restrict__ cscores,
                                             const int* __restrict__ clabels,
                                             const int* __restrict__ ph, const int* __restrict__ pw,
                                             float* __restrict__ out)
{
    int img = blockIdx.x, tid = threadIdx.x;
    __shared__ float sSc[512];
    __shared__ int   sPos[512];
    __shared__ float bx1[400], by1[400], bx2[400], by2[400], sAr[400];
    __shared__ int   sKeep[400], sLbl[400];
    float imgH = (float)ph[0], imgW = (float)pw[0];
    float offm = fmaxf(imgH, imgW) + 1.0f;

    sSc[tid] = (tid < 400) ? cscores[img * 400 + tid] : -3.0f;
    sPos[tid] = tid;
    __syncthreads();

    for (int k = 2; k <= 512; k <<= 1) {
        for (int jj = k >> 1; jj > 0; jj >>= 1) {
            int ixj = tid ^ jj;
            if (ixj > tid) {
                float s1 = sSc[tid], s2 = sSc[ixj];
                int p1 = sPos[tid], p2 = sPos[ixj];
                bool bef = (s1 > s2) || (s1 == s2 && p1 < p2);
                bool sw = ((tid & k) == 0) ? (!bef) : bef;
                if (sw) { sSc[tid] = s2; sSc[ixj] = s1; sPos[tid] = p2; sPos[ixj] = p1; }
            }
            __syncthreads();
        }
    }

    if (tid < 400) {
        int p = sPos[tid];
        int lbl = clabels[img * 400 + p];
        float ofs = (float)lbl * offm;
        float x1 = cboxes[(img * 400 + p) * 4 + 0] + ofs;
        float y1 = cboxes[(img * 400 + p) * 4 + 1] + ofs;
        float x2 = cboxes[(img * 400 + p) * 4 + 2] + ofs;
        float y2 = cboxes[(img * 400 + p) * 4 + 3] + ofs;
        bx1[tid] = x1; by1[tid] = y1; bx2[tid] = x2; by2[tid] = y2;
        sAr[tid] = (x2 - x1) * (y2 - y1);
        sLbl[tid] = lbl;
        sKeep[tid] = (sSc[tid] > 0.05f) ? 1 : 0;
    }
    __syncthreads();

    for (int i = 0; i < 400; ++i) {
        if (sKeep[i]) {
            for (int j2 = i + 1 + tid; j2 < 400; j2 += 512) {
                float ltx = fmaxf(bx1[i], bx1[j2]), lty = fmaxf(by1[i], by1[j2]);
                float rbx = fminf(bx2[i], bx2[j2]), rby = fminf(by2[i], by2[j2]);
                float ww = fmaxf(rbx - ltx, 0.f), hh = fmaxf(rby - lty, 0.f);
                float inter = ww * hh;
                float iou = inter / (((sAr[i] + sAr[j2]) - inter) + 1e-9f);
                if (iou > 0.5f) sKeep[j2] = 0;
            }
        }
        __syncthreads();
    }

    if (tid == 0) {
        int rank = 0;
        for (int i = 0; i < 400 && rank < 100; ++i) {
            if (sKeep[i]) {
                int p = sPos[i];
                for (int kk = 0; kk < 4; ++kk)
                    out[(img * 100 + rank) * 4 + kk] = cboxes[(img * 400 + p) * 4 + kk];
                out[1600 + img * 100 + rank] = sSc[i];
                out[2000 + img * 100 + rank] = (float)sLbl[i];
                ++rank;
            }
        }
        for (; rank < 100; ++rank) {
            for (int kk = 0; kk < 4; ++kk) out[(img * 100 + rank) * 4 + kk] = 0.f;
            out[1600 + img * 100 + rank] = 0.f;
            out[2000 + img * 100 + rank] = -1.0f;
        }
    }
}

// ---------------------------------------------------------------------------
extern "C" void kernel_launch(void* const* d_in, const int* in_sizes, int n_in,
                              void* d_out, int out_size, void* d_ws, size_t ws_size,
                              hipStream_t stream)
{
    const float* f0 = (const float*)d_in[0];
    const float* f1 = (const float*)d_in[1];
    const float* f2 = (const float*)d_in[2];
    const float* f3 = (const float*)d_in[3];
    const float* cls_tw = (const float*)d_in[4];
    const float* cls_tb = (const float*)d_in[5];
    const float* cls_ow = (const float*)d_in[6];
    const float* cls_ob = (const float*)d_in[7];
    const float* reg_tw = (const float*)d_in[8];
    const float* reg_tb = (const float*)d_in[9];
    const float* reg_ow = (const float*)d_in[10];
    const float* reg_ob = (const float*)d_in[11];
    const int* ph = (const int*)d_in[12];
    const int* pw = (const int*)d_in[13];
    float* out = (float*)d_out;

    char* ws = (char*)d_ws;
    size_t off = 0;
    auto alloc = [&](size_t bytes) -> void* {
        void* p = ws + off;
        off = (off + bytes + 1023) & ~(size_t)1023;
        return p;
    };
    const size_t KEYS = (size_t)4 * IMG_KEY * 4;    // 62.7 MB
    const size_t ACT8 = ACT_SLAB * 8;               // 49.3 MB (8 img-head slabs)
    char*     Pin    = (char*)alloc(ACT_SLAB * 4 + 4096);
    char*     slabA  = (char*)alloc((KEYS > ACT8 ? KEYS : ACT8) + 4096);
    unsigned* keys   = (unsigned*)slabA;
    char*     actA   = slabA;
    char*     actB   = (char*)alloc(ACT8 + 4096);
    u16*      repCT  = (u16*)alloc((size_t)16 * WCOG_BYTES);   // 4 layers * 4 cg
    u16*      repRT  = (u16*)alloc((size_t)16 * WCOG_BYTES);
    u16*      repCO  = (u16*)alloc((size_t)12 * WCOG_BYTES);   // 12 cg
    u16*      repRO  = (u16*)alloc((size_t)1 * WCOG_BYTES);
    float*    regb   = (float*)alloc((size_t)4 * IMG_REG * 4);
    unsigned* hist   = (unsigned*)alloc((size_t)16 * HBINS * 4);
    unsigned* cnt    = (unsigned*)alloc(16 * 4);
    unsigned* tbin   = (unsigned*)alloc(16 * 4);
    uint2*    comp   = (uint2*)alloc((size_t)16 * CAP * 8);
    uint2*    topk   = (uint2*)alloc((size_t)1600 * 8);
    float*    cboxes = (float*)alloc((size_t)4 * 400 * 4 * 4);
    float*    cscores= (float*)alloc((size_t)4 * 400 * 4);
    int*      clabels= (int*)alloc((size_t)4 * 400 * 4);

    // zero halos (act slabs must be re-zeroed each launch) + accumulators
    hipMemsetAsync(Pin, 0, ACT_SLAB * 4, stream);
    hipMemsetAsync(actA, 0, ACT8, stream);
    hipMemsetAsync(actB, 0, ACT8, stream);
    hipMemsetAsync(hist, 0, (size_t)16 * HBINS * 4, stream);
    hipMemsetAsync(cnt, 0, 64, stream);

    // prep: pad inputs (f16 hi/lo split), repack weights
    {
        int tPad = 4 * 16 * 2 * 1360;
        pad16_k<<<(tPad + 255) / 256, 256, 0, stream>>>(f0, f1, f2, f3, Pin);
        int tT = 4 * 4 * 16 * 1280;
        repack16_k<<<(tT + 255) / 256, 256, 0, stream>>>(cls_tw, repCT, 256, 4, tT);
        repack16_k<<<(tT + 255) / 256, 256, 0, stream>>>(reg_tw, repRT, 256, 4, tT);
        int tCO = 12 * 16 * 1280;
        repack16_k<<<(tCO + 255) / 256, 256, 0, stream>>>(cls_ow, repCO, 720, 12, tCO);
        int tRO = 16 * 1280;
        repack16_k<<<(tRO + 255) / 256, 256, 0, stream>>>(reg_ow, repRO, 36, 1, tRO);
    }

    const size_t RL = (size_t)4 * 16 * 20480;   // per-layer repack stride (u16 elems)
    // tower: L0 Pin->A, L1 A->B, L2 B->A, L3 A->B
    conv16<<<dim3(43, 4, 8), 256, 0, stream>>>(Pin, Pin, actA,
        repCT, cls_tb, repRT, reg_tb, keys, regb, 0, 1);
    conv16<<<dim3(43, 4, 8), 256, 0, stream>>>(Pin, actA, actB,
        repCT + RL, cls_tb + 256, repRT + RL, reg_tb + 256, keys, regb, 0, 0);
    conv16<<<dim3(43, 4, 8), 256, 0, stream>>>(Pin, actB, actA,
        repCT + 2 * RL, cls_tb + 512, repRT + 2 * RL, reg_tb + 512, keys, regb, 0, 0);
    conv16<<<dim3(43, 4, 8), 256, 0, stream>>>(Pin, actA, actB,
        repCT + 3 * RL, cls_tb + 768, repRT + 3 * RL, reg_tb + 768, keys, regb, 0, 0);
    // out-convs: read B, write keys(=slabA, free now) + regb
    conv16<<<dim3(43, 13, 4), 256, 0, stream>>>(Pin, actB, nullptr,
        repCO, cls_ob, repRO, reg_ob, keys, regb, 1, 0);

    hist_k<<<dim3(180, 16), 256, 0, stream>>>(keys, hist);
    thresh_k<<<16, 256, 0, stream>>>(hist, tbin);
    compact_k<<<dim3(180, 16), 256, 0, stream>>>(keys, tbin, cnt, comp);
    topsort_k<<<16, 256, 0, stream>>>(cnt, comp, topk);
    decode_k<<<16, 128, 0, stream>>>(topk, regb, cboxes, cscores, clabels, ph, pw);
    nms_k<<<4, 512, 0, stream>>>(cboxes, cscores, clabels, ph, pw, out);
}

// Round 2
// 1322.290 us; speedup vs baseline: 3.0924x; 1.1540x over previous
//
#include <hip/hip_runtime.h>
#include <math.h>

#define A_NUM 9
#define NCLS 80
#define IMG_KEY 3916800   // 720*5440
#define IMG_REG 195840    // 36*5440
#define CAP 8192
#define HBINS 16384

// ---- f16 hi/lo split activation & weight layouts --------------------------
// Activations per (img[,head]), per ci16-chunk, per level:
//   slot(16B) = lvlSlot + ((row*2+plane)*2+half)*C + col,  slot holds 8 f16 (ci8)
//   plane: 0=hi, 1=lo ; half: ci bit3 ; row/col padded (+1 halo)
// Levels: L0 66x66, L1 34x34, L2 18x18, L3 10x18 (cols 10..17 stay zero)
#define CHUNK_SLOTS 24064                       // 17424+4624+1296+720
#define CHUNK_BYTES (CHUNK_SLOTS * 16)          // 385024
#define ACT_SLAB ((size_t)CHUNK_BYTES * 16)     // 6160384 B per (img,head)
// Weights per co-group(64), per chunk: [kstep5][tap2][plane2][half2][co64][ci8]
#define WCHUNK_BYTES 40960
#define WCOG_BYTES (WCHUNK_BYTES * 16)          // 655360

typedef _Float16 h8 __attribute__((ext_vector_type(8)));
typedef float fx4 __attribute__((ext_vector_type(4)));
typedef unsigned short u16;

__constant__ int   c_W[4]       = {64, 32, 16, 8};
__constant__ int   c_stride[4]  = {8, 16, 32, 64};
__constant__ float c_sizes[4][3]= {{32.f,40.f,50.f},{64.f,80.f,101.f},{128.f,161.f,203.f},{256.f,322.f,406.f}};
__constant__ int   c_keyOff[4]  = {0, 2949120, 3686400, 3870720};
__constant__ int   c_keyCnt[4]  = {2949120, 737280, 184320, 46080};
__constant__ int   c_regOff[4]  = {0, 147456, 184320, 193536};
__constant__ int   c_C[4]       = {66, 34, 18, 18};
__constant__ int   c_lvlSlot[4] = {0, 17424, 22048, 23344};
__constant__ int   c_pOff[4]    = {0, 1024, 1280, 1344};

// global_load_lds, 16B/lane: LDS dest = wave-uniform base + lane*16.
__device__ __forceinline__ void gl_lds16(const void* g, void* l) {
    __builtin_amdgcn_global_load_lds(
        (const __attribute__((address_space(1))) void*)g,
        (__attribute__((address_space(3))) void*)l, 16, 0, 0);
}

// ---------------------------------------------------------------------------
// prep: pad f0..f3 (fp32) into Pin in f16 hi/lo split layout (interior only;
// halo stays zero from memset). One thread: 8 ci x 4 cols for one (chunk,half).
// ---------------------------------------------------------------------------
__global__ __launch_bounds__(256) void pad16_k(
    const float* __restrict__ f0, const float* __restrict__ f1,
    const float* __restrict__ f2, const float* __restrict__ f3,
    char* __restrict__ Pin)
{
    int idx = blockIdx.x * 256 + threadIdx.x;
    const int PER_IMG = 16 * 2 * 1360;
    if (idx >= 4 * PER_IMG) return;
    int img = idx / PER_IMG;
    int r = idx - img * PER_IMG;
    int chunk = r / (2 * 1360);
    int r2 = r - chunk * (2 * 1360);
    int hfsel = r2 / 1360;
    int p = r2 - hfsel * 1360;
    int lvl = (p < 1024) ? 0 : (p < 1280 ? 1 : (p < 1344 ? 2 : 3));
    int u = p - c_pOff[lvl];
    int sh = 4 - lvl;
    int y = u >> sh;
    int xg = u & ((1 << sh) - 1);
    int x0 = xg * 4;
    int W = 64 >> lvl;
    const float* f = (lvl == 0) ? f0 : (lvl == 1) ? f1 : (lvl == 2) ? f2 : f3;
    int ci0 = chunk * 16 + hfsel * 8;
    float4 v[8];
    #pragma unroll
    for (int j = 0; j < 8; ++j)
        v[j] = *reinterpret_cast<const float4*>(
            f + ((size_t)(img * 256 + ci0 + j)) * (W * W) + y * W + x0);
    char* base = Pin + (size_t)img * ACT_SLAB + (size_t)chunk * CHUNK_BYTES;
    const int C = c_C[lvl];
    size_t rowSlot = (size_t)c_lvlSlot[lvl] + (size_t)((y + 1) * 4 + hfsel) * C;
    #pragma unroll
    for (int c = 0; c < 4; ++c) {
        h8 hv, lv;
        #pragma unroll
        for (int j = 0; j < 8; ++j) {
            float val = (c == 0) ? v[j].x : (c == 1) ? v[j].y : (c == 2) ? v[j].z : v[j].w;
            _Float16 hh = (_Float16)val;
            hv[j] = hh;
            lv[j] = (_Float16)(val - (float)hh);
        }
        size_t slot = rowSlot + (x0 + c + 1);
        *reinterpret_cast<h8*>(base + slot * 16) = hv;                       // hi plane
        *reinterpret_cast<h8*>(base + (slot + 2 * (size_t)C) * 16) = lv;     // lo plane
    }
}

// ---------------------------------------------------------------------------
// prep: repack conv weights fp32 [L][C_out][256][3][3] ->
// per (layer,cg,chunk): [kstep5][tap2][plane2][half2][co64][ci8] f16, kk==9 zero.
// ---------------------------------------------------------------------------
__global__ __launch_bounds__(256) void repack16_k(
    const float* __restrict__ src, u16* __restrict__ dst,
    int C_out, int nCg, int total)
{
    int idx = blockIdx.x * 256 + threadIdx.x;
    if (idx >= total) return;
    int per = nCg * 16 * 1280;
    int layer = idx / per;
    int r = idx - layer * per;
    int cg = r / (16 * 1280);
    int r2 = r - cg * (16 * 1280);
    int chunk = r2 / 1280;
    int s = r2 - chunk * 1280;
    int co = s & 63;
    int r3 = s >> 6;
    int hfsel = r3 & 1;
    int kk = r3 >> 1;                 // 0..9 ; 9 = zero-pad tap
    int coG = cg * 64 + co;
    float v[8];
    if (kk < 9 && coG < C_out) {
        const float* sp = src + ((size_t)(layer * C_out + coG)) * 2304
                        + (size_t)(chunk * 16 + hfsel * 8) * 9 + kk;
        #pragma unroll
        for (int j = 0; j < 8; ++j) v[j] = sp[j * 9];
    } else {
        #pragma unroll
        for (int j = 0; j < 8; ++j) v[j] = 0.f;
    }
    h8 hv, lv;
    #pragma unroll
    for (int j = 0; j < 8; ++j) {
        _Float16 hh = (_Float16)v[j];
        hv[j] = hh;
        lv[j] = (_Float16)(v[j] - (float)hh);
    }
    size_t e = ((size_t)((layer * nCg + cg) * 16 + chunk)) * 20480
             + (size_t)(kk >> 1) * 4096 + (size_t)(kk & 1) * 2048
             + (size_t)hfsel * 512 + (size_t)co * 8;
    *reinterpret_cast<h8*>(dst + e) = hv;             // plane 0 (hi)
    *reinterpret_cast<h8*>(dst + e + 1024) = lv;      // plane 1 (lo)
}

// ---------------------------------------------------------------------------
// Fused 3x3 SAME conv via MFMA f16 hi/lo split (3 mfma: hh + hl + lh), fp32 acc.
// Tile: 16 rows x 16 cols x 64 co. Wave: 4 M-frags(row) x 4 co-tiles(N=16).
// 22 tiles: L0 4x4, L1 2x2, L2 1, L3 1 (rows/cols >=W guarded).
// 1-D grid + XCD remap: mode0 nwg=704=8*88 -> one (img,head) slab per XCD;
// mode1 nwg=1144=8*143 -> 2 XCDs per img. cg/head-output innermost for L2 reuse.
// Staging all via global_load_lds w16: A 1296 slots slot-linear, B 40KB chunk.
// Epilogue 0: per-wave 1KB LDS transpose -> one b128 global store per lane.
// ---------------------------------------------------------------------------
__global__ __launch_bounds__(256, 2) void conv16(
    const char* __restrict__ Pin, const char* __restrict__ bufIn, char* __restrict__ bufOut,
    const u16* __restrict__ repA, const float* __restrict__ bA,
    const u16* __restrict__ repB, const float* __restrict__ bB,
    unsigned* __restrict__ keys, float* __restrict__ regb,
    int mode, int usePin)
{
    const int tid = threadIdx.x;
    const int lane = tid & 63;
    const int wv = tid >> 6;

    int img, head, coBase, C_out, epi, tile;
    if (mode == 0) {
        int hw = blockIdx.x;                       // 704 = 8*88
        int logical = (hw & 7) * 88 + (hw >> 3);
        int z = logical / 88;
        int rem = logical - z * 88;
        tile = rem >> 2;
        coBase = (rem & 3) * 64;
        img = z & 3; head = z >> 2;
        C_out = 256; epi = 0;
    } else {
        int hw = blockIdx.x;                       // 1144 = 8*143
        int logical = (hw & 7) * 143 + (hw >> 3);
        img = logical / 286;
        int rem = logical - img * 286;
        tile = rem / 13;
        int yy = rem - tile * 13;
        if (yy < 12) { head = 0; coBase = yy * 64; C_out = 720; epi = 1; }
        else         { head = 1; coBase = 0;       C_out = 36;  epi = 2; }
    }
    const float* bsel = head ? bB : bA;
    const u16* wsel = head ? repB : repA;
    const char* wBase = (const char*)wsel + (size_t)(coBase >> 6) * WCOG_BYTES;

    int lvl, ty, tx;
    if (tile < 16)      { lvl = 0; ty = tile >> 2; tx = tile & 3; }
    else if (tile < 20) { int u = tile - 16; lvl = 1; ty = u >> 1; tx = u & 1; }
    else if (tile == 20){ lvl = 2; ty = 0; tx = 0; }
    else                { lvl = 3; ty = 0; tx = 0; }
    const int W = 64 >> lvl;
    const int C = c_C[lvl];
    const int tileY = ty * 16, tileX = tx * 16;

    const char* srcB = usePin ? Pin + (size_t)img * ACT_SLAB
                              : bufIn + (size_t)(head * 4 + img) * ACT_SLAB;

    __shared__ alignas(16) char sA[20736];   // [row18][plane2][half2][col18][ci8]
    __shared__ alignas(16) char sB[40960];   // [kstep5][tap2][plane2][half2][co64][ci8]

    const int laneCol = lane & 15;
    const int g = lane >> 4;
    const int halfS = g & 1;
    const int tapS = g >> 1;
    int laneA[5];
    #pragma unroll
    for (int k = 0; k < 5; ++k) {
        int kk = 2 * k + tapS; if (kk > 8) kk = 8;   // kk==9 pairs with zero B
        int ky = kk / 3;
        int kx = kk - ky * 3;
        laneA[k] = ky * 1152 + halfS * 288 + (laneCol + kx) * 16;
    }
    const int laneB = tapS * 4096 + halfS * 1024 + laneCol * 16;

    // A staging: 1296 slots (18 rows incl halo), slot-linear LDS, 6 issues/thread.
    // lvl3 rows>=10 overrun into following chunk region (garbage, outputs guarded).
    int aByte[6]; bool aOk[6];
    #pragma unroll
    for (int p = 0; p < 6; ++p) {
        int s = tid + 256 * p;
        aOk[p] = (s < 1296);
        int sc = aOk[p] ? s : 1295;
        int row = sc / 72;
        int q = sc - row * 72;
        int pl = q / 36;
        int q2 = q - pl * 36;
        int hf = q2 / 18;
        int col = q2 - hf * 18;
        aByte[p] = (c_lvlSlot[lvl] + ((tileY + row) * 4 + pl * 2 + hf) * C
                    + tileX + col) * 16;
    }

    fx4 acc[4][4];
    #pragma unroll
    for (int mt = 0; mt < 4; ++mt)
        #pragma unroll
        for (int nt = 0; nt < 4; ++nt)
            acc[mt][nt] = (fx4){0.f, 0.f, 0.f, 0.f};

    #pragma unroll 1
    for (int ck = 0; ck < 16; ++ck) {
        const char* srcCk = srcB + (size_t)ck * CHUNK_BYTES;
        #pragma unroll
        for (int p = 0; p < 6; ++p)
            if (aOk[p]) gl_lds16(srcCk + aByte[p], (char*)sA + (wv * 64 + 256 * p) * 16);
        const char* wCk = wBase + (size_t)ck * WCHUNK_BYTES;
        for (int j = wv; j < 40; j += 4)
            gl_lds16(wCk + j * 1024 + lane * 16, (char*)sB + j * 1024);
        __syncthreads();   // drains vmcnt -> LDS ready

        #pragma unroll
        for (int k = 0; k < 5; ++k) {
            const char* bk = sB + k * 8192;
            h8 Bh[4], Bl[4];
            #pragma unroll
            for (int nt = 0; nt < 4; ++nt) {
                Bh[nt] = *reinterpret_cast<const h8*>(bk + nt * 256 + laneB);
                Bl[nt] = *reinterpret_cast<const h8*>(bk + 2048 + nt * 256 + laneB);
            }
            #pragma unroll
            for (int mt = 0; mt < 4; ++mt) {
                const char* am = sA + (wv * 4 + mt) * 1152 + laneA[k];
                h8 Ah = *reinterpret_cast<const h8*>(am);
                h8 Al = *reinterpret_cast<const h8*>(am + 576);
                #pragma unroll
                for (int nt = 0; nt < 4; ++nt) {
                    acc[mt][nt] = __builtin_amdgcn_mfma_f32_16x16x32_f16(Ah, Bh[nt], acc[mt][nt], 0, 0, 0);
                    acc[mt][nt] = __builtin_amdgcn_mfma_f32_16x16x32_f16(Ah, Bl[nt], acc[mt][nt], 0, 0, 0);
                    acc[mt][nt] = __builtin_amdgcn_mfma_f32_16x16x32_f16(Al, Bh[nt], acc[mt][nt], 0, 0, 0);
                }
            }
        }
        __syncthreads();
    }

    // ---- epilogue: C frag col(n)=laneCol (co), row(m)=g*4+i (4 consec px)
    const int HW = W * W;
    if (epi == 0) {
        char* dstB = bufOut + (size_t)(head * 4 + img) * ACT_SLAB;
        _Float16* eW = reinterpret_cast<_Float16*>(sB + wv * 1024);  // per-wave 1KB
        const int ci8 = laneCol & 7;
        const int hf  = laneCol >> 3;
        const int rpx = lane & 15, rhalf = (lane >> 4) & 1, rplane = lane >> 5;
        const int rOff = rpx * 32 + rplane * 16 + rhalf * 8;
        const int rx = tileX + rpx;
        #pragma unroll
        for (int mt = 0; mt < 4; ++mt) {
            int y = tileY + wv * 4 + mt;
            bool yok = (y < W);
            #pragma unroll
            for (int nt = 0; nt < 4; ++nt) {
                int coG = coBase + nt * 16 + laneCol;
                float b = bsel[coG];
                #pragma unroll
                for (int i = 0; i < 4; ++i) {
                    float v = fmaxf(acc[mt][nt][i] + b, 0.f);
                    _Float16 hh = (_Float16)v;
                    _Float16 ll = (_Float16)(v - (float)hh);
                    int px = g * 4 + i;
                    eW[px * 32 + hf * 8 + ci8] = hh;          // plane 0
                    eW[px * 32 + 16 + hf * 8 + ci8] = ll;     // plane 1
                }
                __syncthreads();
                if (yok && rx < W) {
                    int chunkIdx = (coBase + nt * 16) >> 4;
                    size_t slot = (size_t)chunkIdx * CHUNK_SLOTS + c_lvlSlot[lvl]
                                + (size_t)(((y + 1) * 2 + rplane) * 2 + rhalf) * C + (rx + 1);
                    *reinterpret_cast<h8*>(dstB + slot * 16) =
                        *reinterpret_cast<const h8*>(eW + rOff);
                }
                __syncthreads();
            }
        }
    } else if (epi == 1) {
        unsigned* kb = keys + (size_t)img * IMG_KEY + c_keyOff[lvl];
        #pragma unroll
        for (int mt = 0; mt < 4; ++mt) {
            int y = tileY + wv * 4 + mt;
            int x0 = tileX + g * 4;
            if (y >= W || x0 >= W) continue;
            #pragma unroll
            for (int nt = 0; nt < 4; ++nt) {
                int coG = coBase + nt * 16 + laneCol;
                if (coG >= C_out) continue;
                float b = bsel[coG];
                unsigned kq[4];
                #pragma unroll
                for (int i = 0; i < 4; ++i) {
                    float sc = 1.0f / (1.0f + expf(-(acc[mt][nt][i] + b)));
                    kq[i] = (sc > 0.05f) ? __float_as_uint(sc) : 0u;
                }
                *reinterpret_cast<uint4*>(kb + (size_t)coG * HW + y * W + x0) =
                    make_uint4(kq[0], kq[1], kq[2], kq[3]);
            }
        }
    } else {
        float* rb = regb + (size_t)img * IMG_REG + c_regOff[lvl];
        #pragma unroll
        for (int mt = 0; mt < 4; ++mt) {
            int y = tileY + wv * 4 + mt;
            if (y >= W) continue;
            #pragma unroll
            for (int nt = 0; nt < 4; ++nt) {
                int coG = nt * 16 + laneCol;
                if (coG >= C_out) continue;
                float b = bsel[coG];
                int a = coG >> 2, jj = coG & 3;
                #pragma unroll
                for (int i = 0; i < 4; ++i) {
                    int x = tileX + g * 4 + i;
                    if (x >= W) continue;
                    rb[((size_t)(y * W + x) * A_NUM + a) * 4 + jj] = acc[mt][nt][i] + b;
                }
            }
        }
    }
}

// ---------------------------------------------------------------------------
__global__ __launch_bounds__(256) void hist_k(const unsigned* __restrict__ keys,
                                              unsigned* __restrict__ hist)
{
    int il = blockIdx.y, img = il >> 2, lvl = il & 3;
    int n = c_keyCnt[lvl];
    int chunk = blockIdx.x * 16384;
    if (chunk >= n) return;
    __shared__ unsigned h[HBINS];
    for (int t = threadIdx.x; t < HBINS; t += 256) h[t] = 0;
    __syncthreads();
    const uint4* k4 = (const uint4*)(keys + (size_t)img * IMG_KEY + c_keyOff[lvl]);
    int i0 = chunk >> 2, i1 = min(chunk + 16384, n) >> 2;
    for (int i = i0 + (int)threadIdx.x; i < i1; i += 256) {
        uint4 kv = k4[i];
        if (kv.x) atomicAdd(&h[kv.x >> 18], 1u);
        if (kv.y) atomicAdd(&h[kv.y >> 18], 1u);
        if (kv.z) atomicAdd(&h[kv.z >> 18], 1u);
        if (kv.w) atomicAdd(&h[kv.w >> 18], 1u);
    }
    __syncthreads();
    unsigned* gh = hist + (size_t)il * HBINS;
    for (int t = threadIdx.x; t < HBINS; t += 256)
        if (h[t]) atomicAdd(&gh[t], h[t]);
}

__global__ __launch_bounds__(256) void thresh_k(const unsigned* __restrict__ hist,
                                                unsigned* __restrict__ tbin)
{
    const unsigned* h = hist + (size_t)blockIdx.x * HBINS;
    __shared__ unsigned cs[256];
    int tid = threadIdx.x;
    unsigned s = 0;
    int base = tid * 64;
    for (int q = 0; q < 64; ++q) { int b = base + q; if (b >= 1) s += h[b]; }
    cs[tid] = s;
    __syncthreads();
    if (tid == 0) {
        unsigned total = 0, sel = 0;
        for (int c = 255; c >= 0; --c) {
            if (total + cs[c] >= 100u) {
                int lo = (c == 0) ? 1 : c * 64;
                for (int b = c * 64 + 63; b >= lo; --b) {
                    total += h[b];
                    if (total >= 100u) { sel = (unsigned)b; break; }
                }
                break;
            }
            total += cs[c];
        }
        tbin[blockIdx.x] = sel;
    }
}

__global__ __launch_bounds__(256) void compact_k(const unsigned* __restrict__ keys,
                                                 const unsigned* __restrict__ tbin,
                                                 unsigned* __restrict__ cnt,
                                                 uint2* __restrict__ comp)
{
    int il = blockIdx.y, img = il >> 2, lvl = il & 3;
    int n = c_keyCnt[lvl];
    int chunk = blockIdx.x * 16384;
    if (chunk >= n) return;
    const uint4* k4 = (const uint4*)(keys + (size_t)img * IMG_KEY + c_keyOff[lvl]);
    unsigned thr = tbin[il] << 18;
    int shift = 12 - 2 * lvl;
    int hwm = (1 << shift) - 1;
    int i0 = chunk >> 2, i1 = min(chunk + 16384, n) >> 2;
    __shared__ unsigned lcnt, lbase, lcur;
    if (threadIdx.x == 0) { lcnt = 0; lcur = 0; }
    __syncthreads();
    unsigned myc = 0;
    for (int i = i0 + (int)threadIdx.x; i < i1; i += 256) {
        uint4 kv = k4[i];
        myc += (kv.x != 0u && kv.x >= thr);
        myc += (kv.y != 0u && kv.y >= thr);
        myc += (kv.z != 0u && kv.z >= thr);
        myc += (kv.w != 0u && kv.w >= thr);
    }
    if (myc) atomicAdd(&lcnt, myc);
    __syncthreads();
    if (threadIdx.x == 0 && lcnt) lbase = atomicAdd(&cnt[il], lcnt);
    __syncthreads();
    if (lcnt == 0) return;
    uint2* c = comp + (size_t)il * CAP;
    for (int i = i0 + (int)threadIdx.x; i < i1; i += 256) {
        uint4 kv = k4[i];
        unsigned kk[4] = {kv.x, kv.y, kv.z, kv.w};
        #pragma unroll
        for (int j = 0; j < 4; ++j) {
            unsigned key = kk[j];
            if (key != 0u && key >= thr) {
                int t = i * 4 + j;
                int co = t >> shift, p = t & hwm;
                int a = co / NCLS, cls = co - a * NCLS;
                unsigned idx = (unsigned)((p * A_NUM + a) * NCLS + cls);
                unsigned pos = lbase + atomicAdd(&lcur, 1u);
                if (pos < CAP) c[pos] = make_uint2(key, idx);
            }
        }
    }
}

__global__ __launch_bounds__(256) void topsort_k(const unsigned* __restrict__ cnt,
                                                 const uint2* __restrict__ comp,
                                                 uint2* __restrict__ topk)
{
    __shared__ unsigned long long s[CAP];
    int il = blockIdx.x, tid = threadIdx.x;
    int n = (int)min(cnt[il], (unsigned)CAP);
    const uint2* c = comp + (size_t)il * CAP;
    for (int i = tid; i < CAP; i += 256) {
        unsigned long long v = 0ull;
        if (i < n) {
            uint2 e = c[i];
            v = ((unsigned long long)e.x << 32) | (unsigned long long)(~e.y);
        }
        s[i] = v;
    }
    for (int k = 2; k <= CAP; k <<= 1) {
        for (int j = k >> 1; j > 0; j >>= 1) {
            __syncthreads();
            for (int p = tid; p < CAP / 2; p += 256) {
                int i = ((p & ~(j - 1)) << 1) | (p & (j - 1));
                int ixj = i | j;
                unsigned long long a = s[i], b = s[ixj];
                if (((i & k) == 0) ? (a < b) : (a > b)) { s[i] = b; s[ixj] = a; }
            }
        }
    }
    __syncthreads();
    if (tid < 100) {
        unsigned long long v = s[tid];
        topk[il * 100 + tid] = make_uint2((unsigned)(v >> 32), ~(unsigned)(v & 0xFFFFFFFFull));
    }
}

// ---------------------------------------------------------------------------
__global__ void decode_k(const uint2* __restrict__ topk, const float* __restrict__ regb,
                         float* __restrict__ cboxes, float* __restrict__ cscores,
                         int* __restrict__ clabels, const int* __restrict__ ph, const int* __restrict__ pw)
{
    int il = blockIdx.x, img = il >> 2, lvl = il & 3;
    int j = threadIdx.x;
    if (j >= 100) return;
    float imgW = (float)pw[0], imgH = (float)ph[0];
    uint2 tk = topk[il * 100 + j];
    int outP = img * 400 + lvl * 100 + j;
    if (tk.x == 0u) {
        cboxes[outP * 4 + 0] = 0.f; cboxes[outP * 4 + 1] = 0.f;
        cboxes[outP * 4 + 2] = 0.f; cboxes[outP * 4 + 3] = 0.f;
        cscores[outP] = -1.0f; clabels[outP] = -1;
        return;
    }
    float score = __uint_as_float(tk.x);
    unsigned idx = tk.y;
    int aidx = (int)(idx / NCLS);
    int lbl  = (int)(idx - (unsigned)aidx * NCLS);
    int a = aidx % A_NUM, p = aidx / A_NUM;
    int W = c_W[lvl];
    int y = p / W, x = p - y * W;
    int r = a / 3, si = a - r * 3;
    float ratio = (r == 0) ? 0.5f : ((r == 1) ? 1.0f : 2.0f);
    float size = c_sizes[lvl][si];
    float hr = sqrtf(ratio);
    float wr = 1.0f / hr;
    float wsz = wr * size, hsz = hr * size;
    float bw = rintf(wsz * 0.5f), bh = rintf(hsz * 0.5f);
    float sx = (float)(x * c_stride[lvl]), sy = (float)(y * c_stride[lvl]);
    float ax1 = fminf(fmaxf(sx - bw, 0.f), imgW);
    float ay1 = fminf(fmaxf(sy - bh, 0.f), imgH);
    float ax2 = fminf(fmaxf(sx + bw, 0.f), imgW);
    float ay2 = fminf(fmaxf(sy + bh, 0.f), imgH);
    float aw = ax2 - ax1, ah = ay2 - ay1;
    float cx = ax1 + 0.5f * aw, cy = ay1 + 0.5f * ah;
    const float* rel = regb + (size_t)img * IMG_REG + c_regOff[lvl] + (size_t)aidx * 4;
    float dx = rel[0], dy = rel[1];
    float dw = fminf(rel[2], 4.135166556742356f);
    float dh = fminf(rel[3], 4.135166556742356f);
    float pcx = dx * aw + cx, pcy = dy * ah + cy;
    float pwd = expf(dw) * aw, phd = expf(dh) * ah;
    float x1 = pcx - 0.5f * pwd, y1 = pcy - 0.5f * phd;
    float x2 = pcx + 0.5f * pwd, y2 = pcy + 0.5f * phd;
    cboxes[outP * 4 + 0] = fminf(fmaxf(x1, 0.f), imgW);
    cboxes[outP * 4 + 1] = fminf(fmaxf(y1, 0.f), imgH);
    cboxes[outP * 4 + 2] = fminf(fmaxf(x2, 0.f), imgW);
    cboxes[outP * 4 + 3] = fminf(fmaxf(y2, 0.f), imgH);
    cscores[outP] = score;
    clabels[outP] = lbl;
}

__global__ __launch_bounds__(512) void nms_k(const float* __restrict__ cboxes,
                                             const float* __restrict__ cscores,
                                             const int* __restrict__ clabels,
                                             const int* __restrict__ ph, const int* __restrict__ pw,
                                             float* __restrict__ out)
{
    int img = blockIdx.x, tid = threadIdx.x;
    __shared__ float sSc[512];
    __shared__ int   sPos[512];
    __shared__ float bx1[400], by1[400], bx2[400], by2[400], sAr[400];
    __shared__ int   sKeep[400], sLbl[400];
    float imgH = (float)ph[0], imgW = (float)pw[0];
    float offm = fmaxf(imgH, imgW) + 1.0f;

    sSc[tid] = (tid < 400) ? cscores[img * 400 + tid] : -3.0f;
    sPos[tid] = tid;
    __syncthreads();

    for (int k = 2; k <= 512; k <<= 1) {
        for (int jj = k >> 1; jj > 0; jj >>= 1) {
            int ixj = tid ^ jj;
            if (ixj > tid) {
                float s1 = sSc[tid], s2 = sSc[ixj];
                int p1 = sPos[tid], p2 = sPos[ixj];
                bool bef = (s1 > s2) || (s1 == s2 && p1 < p2);
                bool sw = ((tid & k) == 0) ? (!bef) : bef;
                if (sw) { sSc[tid] = s2; sSc[ixj] = s1; sPos[tid] = p2; sPos[ixj] = p1; }
            }
            __syncthreads();
        }
    }

    if (tid < 400) {
        int p = sPos[tid];
        int lbl = clabels[img * 400 + p];
        float ofs = (float)lbl * offm;
        float x1 = cboxes[(img * 400 + p) * 4 + 0] + ofs;
        float y1 = cboxes[(img * 400 + p) * 4 + 1] + ofs;
        float x2 = cboxes[(img * 400 + p) * 4 + 2] + ofs;
        float y2 = cboxes[(img * 400 + p) * 4 + 3] + ofs;
        bx1[tid] = x1; by1[tid] = y1; bx2[tid] = x2; by2[tid] = y2;
        sAr[tid] = (x2 - x1) * (y2 - y1);
        sLbl[tid] = lbl;
        sKeep[tid] = (sSc[tid] > 0.05f) ? 1 : 0;
    }
    __syncthreads();

    for (int i = 0; i < 400; ++i) {
        if (sKeep[i]) {
            for (int j2 = i + 1 + tid; j2 < 400; j2 += 512) {
                float ltx = fmaxf(bx1[i], bx1[j2]), lty = fmaxf(by1[i], by1[j2]);
                float rbx = fminf(bx2[i], bx2[j2]), rby = fminf(by2[i], by2[j2]);
                float ww = fmaxf(rbx - ltx, 0.f), hh = fmaxf(rby - lty, 0.f);
                float inter = ww * hh;
                float iou = inter / (((sAr[i] + sAr[j2]) - inter) + 1e-9f);
                if (iou > 0.5f) sKeep[j2] = 0;
            }
        }
        __syncthreads();
    }

    if (tid == 0) {
        int rank = 0;
        for (int i = 0; i < 400 && rank < 100; ++i) {
            if (sKeep[i]) {
                int p = sPos[i];
                for (int kk = 0; kk < 4; ++kk)
                    out[(img * 100 + rank) * 4 + kk] = cboxes[(img * 400 + p) * 4 + kk];
                out[1600 + img * 100 + rank] = sSc[i];
                out[2000 + img * 100 + rank] = (float)sLbl[i];
                ++rank;
            }
        }
        for (; rank < 100; ++rank) {
            for (int kk = 0; kk < 4; ++kk) out[(img * 100 + rank) * 4 + kk] = 0.f;
            out[1600 + img * 100 + rank] = 0.f;
            out[2000 + img * 100 + rank] = -1.0f;
        }
    }
}

// ---------------------------------------------------------------------------
extern "C" void kernel_launch(void* const* d_in, const int* in_sizes, int n_in,
                              void* d_out, int out_size, void* d_ws, size_t ws_size,
                              hipStream_t stream)
{
    const float* f0 = (const float*)d_in[0];
    const float* f1 = (const float*)d_in[1];
    const float* f2 = (const float*)d_in[2];
    const float* f3 = (const float*)d_in[3];
    const float* cls_tw = (const float*)d_in[4];
    const float* cls_tb = (const float*)d_in[5];
    const float* cls_ow = (const float*)d_in[6];
    const float* cls_ob = (const float*)d_in[7];
    const float* reg_tw = (const float*)d_in[8];
    const float* reg_tb = (const float*)d_in[9];
    const float* reg_ow = (const float*)d_in[10];
    const float* reg_ob = (const float*)d_in[11];
    const int* ph = (const int*)d_in[12];
    const int* pw = (const int*)d_in[13];
    float* out = (float*)d_out;

    char* ws = (char*)d_ws;
    size_t off = 0;
    auto alloc = [&](size_t bytes) -> void* {
        void* p = ws + off;
        off = (off + bytes + 1023) & ~(size_t)1023;
        return p;
    };
    const size_t KEYS = (size_t)4 * IMG_KEY * 4;    // 62.7 MB
    const size_t ACT8 = ACT_SLAB * 8;               // 49.3 MB (8 img-head slabs)
    // +32KB slack: lvl3 16-row staging reads overrun chunk/slab ends (discarded)
    char*     Pin    = (char*)alloc(ACT_SLAB * 4 + 32768);
    char*     slabA  = (char*)alloc((KEYS > ACT8 ? KEYS : ACT8) + 32768);
    unsigned* keys   = (unsigned*)slabA;
    char*     actA   = slabA;
    char*     actB   = (char*)alloc(ACT8 + 32768);
    u16*      repCT  = (u16*)alloc((size_t)16 * WCOG_BYTES);   // 4 layers * 4 cg
    u16*      repRT  = (u16*)alloc((size_t)16 * WCOG_BYTES);
    u16*      repCO  = (u16*)alloc((size_t)12 * WCOG_BYTES);   // 12 cg
    u16*      repRO  = (u16*)alloc((size_t)1 * WCOG_BYTES);
    float*    regb   = (float*)alloc((size_t)4 * IMG_REG * 4);
    unsigned* hist   = (unsigned*)alloc((size_t)16 * HBINS * 4);
    unsigned* cnt    = (unsigned*)alloc(16 * 4);
    unsigned* tbin   = (unsigned*)alloc(16 * 4);
    uint2*    comp   = (uint2*)alloc((size_t)16 * CAP * 8);
    uint2*    topk   = (uint2*)alloc((size_t)1600 * 8);
    float*    cboxes = (float*)alloc((size_t)4 * 400 * 4 * 4);
    float*    cscores= (float*)alloc((size_t)4 * 400 * 4);
    int*      clabels= (int*)alloc((size_t)4 * 400 * 4);

    // zero halos (act slabs must be re-zeroed each launch) + accumulators
    hipMemsetAsync(Pin, 0, ACT_SLAB * 4, stream);
    hipMemsetAsync(actA, 0, ACT8, stream);
    hipMemsetAsync(actB, 0, ACT8, stream);
    hipMemsetAsync(hist, 0, (size_t)16 * HBINS * 4, stream);
    hipMemsetAsync(cnt, 0, 64, stream);

    // prep: pad inputs (f16 hi/lo split), repack weights
    {
        int tPad = 4 * 16 * 2 * 1360;
        pad16_k<<<(tPad + 255) / 256, 256, 0, stream>>>(f0, f1, f2, f3, Pin);
        int tT = 4 * 4 * 16 * 1280;
        repack16_k<<<(tT + 255) / 256, 256, 0, stream>>>(cls_tw, repCT, 256, 4, tT);
        repack16_k<<<(tT + 255) / 256, 256, 0, stream>>>(reg_tw, repRT, 256, 4, tT);
        int tCO = 12 * 16 * 1280;
        repack16_k<<<(tCO + 255) / 256, 256, 0, stream>>>(cls_ow, repCO, 720, 12, tCO);
        int tRO = 16 * 1280;
        repack16_k<<<(tRO + 255) / 256, 256, 0, stream>>>(reg_ow, repRO, 36, 1, tRO);
    }

    const size_t RL = (size_t)4 * 16 * 20480;   // per-layer repack stride (u16 elems)
    // tower: L0 Pin->A, L1 A->B, L2 B->A, L3 A->B  (1-D grid, XCD-remapped)
    conv16<<<704, 256, 0, stream>>>(Pin, Pin, actA,
        repCT, cls_tb, repRT, reg_tb, keys, regb, 0, 1);
    conv16<<<704, 256, 0, stream>>>(Pin, actA, actB,
        repCT + RL, cls_tb + 256, repRT + RL, reg_tb + 256, keys, regb, 0, 0);
    conv16<<<704, 256, 0, stream>>>(Pin, actB, actA,
        repCT + 2 * RL, cls_tb + 512, repRT + 2 * RL, reg_tb + 512, keys, regb, 0, 0);
    conv16<<<704, 256, 0, stream>>>(Pin, actA, actB,
        repCT + 3 * RL, cls_tb + 768, repRT + 3 * RL, reg_tb + 768, keys, regb, 0, 0);
    // out-convs: read B, write keys(=slabA, free now) + regb
    conv16<<<1144, 256, 0, stream>>>(Pin, actB, nullptr,
        repCO, cls_ob, repRO, reg_ob, keys, regb, 1, 0);

    hist_k<<<dim3(180, 16), 256, 0, stream>>>(keys, hist);
    thresh_k<<<16, 256, 0, stream>>>(hist, tbin);
    compact_k<<<dim3(180, 16), 256, 0, stream>>>(keys, tbin, cnt, comp);
    topsort_k<<<16, 256, 0, stream>>>(cnt, comp, topk);
    decode_k<<<16, 128, 0, stream>>>(topk, regb, cboxes, cscores, clabels, ph, pw);
    nms_k<<<4, 512, 0, stream>>>(cboxes, cscores, clabels, ph, pw, out);
}

// Round 4
// 1313.940 us; speedup vs baseline: 3.1121x; 1.0064x over previous
//
#include <hip/hip_runtime.h>
#include <math.h>

#define A_NUM 9
#define NCLS 80
#define IMG_KEY 3916800   // 720*5440
#define IMG_REG 195840    // 36*5440
#define CAP 8192
#define HBINS 16384

// ---- f16 hi/lo PLANE-MAJOR activation & weight layouts --------------------
// Activations per (img[,head]), per ci16-chunk: [plane2][lvl][row][half2][col]
//   slot(16B) = plane*12032 + plvlSlot + (row*2+half)*C + col ; slot = 8 f16 (ci8)
// Levels (padded +1 halo): L0 66x66, L1 34x34, L2 18x18, L3 10x18
#define PCHUNK 12032                            // slots per plane per chunk
#define CHUNK_SLOTS 24064
#define CHUNK_BYTES (CHUNK_SLOTS * 16)          // 385024
#define ACT_SLAB ((size_t)CHUNK_BYTES * 16)     // 6160384 B per (img,head)
// Weights per cg(64co), per chunk: [plane2][kstep5][tap2][half2][co64][ci8]
//   hi = 20480B, lo = +20480B
#define WCHUNK_BYTES 40960
#define WCOG_BYTES (WCHUNK_BYTES * 16)          // 655360

typedef _Float16 h8 __attribute__((ext_vector_type(8)));
typedef float fx4 __attribute__((ext_vector_type(4)));
typedef unsigned short u16;

__constant__ int   c_W[4]       = {64, 32, 16, 8};
__constant__ int   c_stride[4]  = {8, 16, 32, 64};
__constant__ float c_sizes[4][3]= {{32.f,40.f,50.f},{64.f,80.f,101.f},{128.f,161.f,203.f},{256.f,322.f,406.f}};
__constant__ int   c_keyOff[4]  = {0, 2949120, 3686400, 3870720};
__constant__ int   c_keyCnt[4]  = {2949120, 737280, 184320, 46080};
__constant__ int   c_regOff[4]  = {0, 147456, 184320, 193536};
__constant__ int   c_C[4]       = {66, 34, 18, 18};
__constant__ int   c_plvl[4]    = {0, 8712, 11024, 11672};
__constant__ int   c_pOff[4]    = {0, 1024, 1280, 1344};

// global_load_lds, 16B/lane: LDS dest = wave-uniform base + lane*16.
__device__ __forceinline__ void gl_lds16(const void* g, void* l) {
    __builtin_amdgcn_global_load_lds(
        (const __attribute__((address_space(1))) void*)g,
        (__attribute__((address_space(3))) void*)l, 16, 0, 0);
}

// ---------------------------------------------------------------------------
// prep: pad f0..f3 (fp32) into Pin, plane-major f16 hi/lo layout (interior;
// halo stays zero from memset). One thread: 8 ci x 4 cols for one (chunk,half).
// ---------------------------------------------------------------------------
__global__ __launch_bounds__(256) void pad16_k(
    const float* __restrict__ f0, const float* __restrict__ f1,
    const float* __restrict__ f2, const float* __restrict__ f3,
    char* __restrict__ Pin)
{
    int idx = blockIdx.x * 256 + threadIdx.x;
    const int PER_IMG = 16 * 2 * 1360;
    if (idx >= 4 * PER_IMG) return;
    int img = idx / PER_IMG;
    int r = idx - img * PER_IMG;
    int chunk = r / (2 * 1360);
    int r2 = r - chunk * (2 * 1360);
    int hfsel = r2 / 1360;
    int p = r2 - hfsel * 1360;
    int lvl = (p < 1024) ? 0 : (p < 1280 ? 1 : (p < 1344 ? 2 : 3));
    int u = p - c_pOff[lvl];
    int sh = 4 - lvl;
    int y = u >> sh;
    int xg = u & ((1 << sh) - 1);
    int x0 = xg * 4;
    int W = 64 >> lvl;
    const float* f = (lvl == 0) ? f0 : (lvl == 1) ? f1 : (lvl == 2) ? f2 : f3;
    int ci0 = chunk * 16 + hfsel * 8;
    float4 v[8];
    #pragma unroll
    for (int j = 0; j < 8; ++j)
        v[j] = *reinterpret_cast<const float4*>(
            f + ((size_t)(img * 256 + ci0 + j)) * (W * W) + y * W + x0);
    char* base = Pin + (size_t)img * ACT_SLAB + (size_t)chunk * CHUNK_BYTES;
    const int C = c_C[lvl];
    size_t rowSlot = (size_t)c_plvl[lvl] + (size_t)((y + 1) * 2 + hfsel) * C;
    #pragma unroll
    for (int c = 0; c < 4; ++c) {
        h8 hv, lv;
        #pragma unroll
        for (int j = 0; j < 8; ++j) {
            float val = (c == 0) ? v[j].x : (c == 1) ? v[j].y : (c == 2) ? v[j].z : v[j].w;
            _Float16 hh = (_Float16)val;
            hv[j] = hh;
            lv[j] = (_Float16)(val - (float)hh);
        }
        size_t slot = rowSlot + (x0 + c + 1);
        *reinterpret_cast<h8*>(base + slot * 16) = hv;                         // hi plane
        *reinterpret_cast<h8*>(base + (slot + PCHUNK) * 16) = lv;              // lo plane
    }
}

// ---------------------------------------------------------------------------
// prep: repack conv weights fp32 [L][C_out][256][3][3] ->
// per (layer,cg,chunk): [plane2][kstep5][tap2][half2][co64][ci8] f16, kk==9 zero.
// ---------------------------------------------------------------------------
__global__ __launch_bounds__(256) void repack16_k(
    const float* __restrict__ src, u16* __restrict__ dst,
    int C_out, int nCg, int total)
{
    int idx = blockIdx.x * 256 + threadIdx.x;
    if (idx >= total) return;
    int per = nCg * 16 * 1280;
    int layer = idx / per;
    int r = idx - layer * per;
    int cg = r / (16 * 1280);
    int r2 = r - cg * (16 * 1280);
    int chunk = r2 / 1280;
    int s = r2 - chunk * 1280;
    int co = s & 63;
    int r3 = s >> 6;
    int hfsel = r3 & 1;
    int kk = r3 >> 1;                 // 0..9 ; 9 = zero-pad tap
    int coG = cg * 64 + co;
    float v[8];
    if (kk < 9 && coG < C_out) {
        const float* sp = src + ((size_t)(layer * C_out + coG)) * 2304
                        + (size_t)(chunk * 16 + hfsel * 8) * 9 + kk;
        #pragma unroll
        for (int j = 0; j < 8; ++j) v[j] = sp[j * 9];
    } else {
        #pragma unroll
        for (int j = 0; j < 8; ++j) v[j] = 0.f;
    }
    h8 hv, lv;
    #pragma unroll
    for (int j = 0; j < 8; ++j) {
        _Float16 hh = (_Float16)v[j];
        hv[j] = hh;
        lv[j] = (_Float16)(v[j] - (float)hh);
    }
    size_t e = ((size_t)((layer * nCg + cg) * 16 + chunk)) * 20480
             + (size_t)(kk >> 1) * 2048 + (size_t)(kk & 1) * 1024
             + (size_t)hfsel * 512 + (size_t)co * 8;
    *reinterpret_cast<h8*>(dst + e) = hv;              // hi plane
    *reinterpret_cast<h8*>(dst + e + 10240) = lv;      // lo plane
}

// ---------------------------------------------------------------------------
// Fused 3x3 SAME conv via MFMA f16 hi/lo split (3 mfma: hh + hl + lh), fp32 acc.
// Tile: 16 rows x 16 cols x 64 co. Wave: 4 M-frags(row) x 4 co-tiles(N=16).
// OPERAND SOURCE SPLIT (v3): hi-planes staged in LDS (31KB, global_load_lds);
// lo-planes read per-use directly from global (L1/L2-hot, B-lo depth-1 prefetch).
// Halves LDS read traffic (the measured wall) and allows 3 blocks/CU ->
// tower grid 704 fully resident (sched util 69%->92%).
// MFMA order per acc unchanged (hh,hl,lh) -> bit-identical to v2.
// ---------------------------------------------------------------------------
__global__ __launch_bounds__(256, 3) void conv16(
    const char* __restrict__ Pin, const char* __restrict__ bufIn, char* __restrict__ bufOut,
    const u16* __restrict__ repA, const float* __restrict__ bA,
    const u16* __restrict__ repB, const float* __restrict__ bB,
    unsigned* __restrict__ keys, float* __restrict__ regb,
    int mode, int usePin)
{
    const int tid = threadIdx.x;
    const int lane = tid & 63;
    const int wv = tid >> 6;

    int img, head, coBase, C_out, epi, tile;
    if (mode == 0) {
        int hw = blockIdx.x;                       // 704 = 8*88
        int logical = (hw & 7) * 88 + (hw >> 3);
        int z = logical / 88;
        int rem = logical - z * 88;
        tile = rem >> 2;
        coBase = (rem & 3) * 64;
        img = z & 3; head = z >> 2;
        C_out = 256; epi = 0;
    } else {
        int hw = blockIdx.x;                       // 1144 = 8*143
        int logical = (hw & 7) * 143 + (hw >> 3);
        img = logical / 286;
        int rem = logical - img * 286;
        tile = rem / 13;
        int yy = rem - tile * 13;
        if (yy < 12) { head = 0; coBase = yy * 64; C_out = 720; epi = 1; }
        else         { head = 1; coBase = 0;       C_out = 36;  epi = 2; }
    }
    const float* bsel = head ? bB : bA;
    const u16* wsel = head ? repB : repA;
    const char* wBase = (const char*)wsel + (size_t)(coBase >> 6) * WCOG_BYTES;

    int lvl, ty, tx;
    if (tile < 16)      { lvl = 0; ty = tile >> 2; tx = tile & 3; }
    else if (tile < 20) { int u = tile - 16; lvl = 1; ty = u >> 1; tx = u & 1; }
    else if (tile == 20){ lvl = 2; ty = 0; tx = 0; }
    else                { lvl = 3; ty = 0; tx = 0; }
    const int W = 64 >> lvl;
    const int C = c_C[lvl];
    const int plvl = c_plvl[lvl];
    const int tileY = ty * 16, tileX = tx * 16;

    const char* srcB = usePin ? Pin + (size_t)img * ACT_SLAB
                              : bufIn + (size_t)(head * 4 + img) * ACT_SLAB;

    __shared__ alignas(16) char sA[10368];   // hi: [row18][half2][col18][ci8]
    __shared__ alignas(16) char sB[20480];   // hi: [kstep5][tap2][half2][co64][ci8]

    const int laneCol = lane & 15;
    const int g = lane >> 4;
    const int halfS = g & 1;
    const int tapS = g >> 1;
    const int laneBv = tapS * 2048 + halfS * 1024 + laneCol * 16;
    int laneAhi[5];     // LDS byte offsets (row-relative)
    int AloOff[5];      // global byte offsets within chunk (lo plane, wave rows folded)
    #pragma unroll
    for (int k = 0; k < 5; ++k) {
        int kk = 2 * k + tapS; if (kk > 8) kk = 8;   // kk==9 pairs with zero B
        int ky = kk / 3;
        int kx = kk - ky * 3;
        laneAhi[k] = ky * 576 + halfS * 288 + (laneCol + kx) * 16;
        AloOff[k] = PCHUNK * 16
                  + (plvl + ((tileY + wv * 4 + ky) * 2 + halfS) * C
                     + tileX + laneCol + kx) * 16;
    }
    const int mtStride = 2 * C * 16;     // one image row in plane region

    // A-hi staging: 648 slots of 16B, slot-linear, 3 issues/thread.
    int aByte[3]; bool aOk[3];
    #pragma unroll
    for (int p = 0; p < 3; ++p) {
        int s = tid + 256 * p;
        aOk[p] = (s < 648);
        int sc = aOk[p] ? s : 647;
        int row = sc / 36;
        int q = sc - row * 36;
        int hf = q / 18;
        int col = q - hf * 18;
        aByte[p] = (plvl + ((tileY + row) * 2 + hf) * C + tileX + col) * 16;
    }

    fx4 acc[4][4];
    #pragma unroll
    for (int mt = 0; mt < 4; ++mt)
        #pragma unroll
        for (int nt = 0; nt < 4; ++nt)
            acc[mt][nt] = (fx4){0.f, 0.f, 0.f, 0.f};

    #pragma unroll 1
    for (int ck = 0; ck < 16; ++ck) {
        const char* srcCk = srcB + (size_t)ck * CHUNK_BYTES;
        const char* wCk = wBase + (size_t)ck * WCHUNK_BYTES;
        const char* wLo = wCk + 20480;

        // B-lo k=0 prefetch (global, independent of staging -> hides under drain)
        h8 Bl[2][4];
        #pragma unroll
        for (int nt = 0; nt < 4; ++nt)
            Bl[0][nt] = *reinterpret_cast<const h8*>(wLo + laneBv + nt * 256);

        // hi staging via async global->LDS
        #pragma unroll
        for (int p = 0; p < 3; ++p)
            if (aOk[p]) gl_lds16(srcCk + aByte[p], (char*)sA + (wv * 64 + 256 * p) * 16);
        for (int j = wv; j < 20; j += 4)
            gl_lds16(wCk + j * 1024 + lane * 16, (char*)sB + j * 1024);
        __syncthreads();   // drains vmcnt -> LDS ready

        #pragma unroll
        for (int k = 0; k < 5; ++k) {
            if (k < 4) {   // B-lo depth-1 prefetch
                const char* wn = wLo + (k + 1) * 4096;
                #pragma unroll
                for (int nt = 0; nt < 4; ++nt)
                    Bl[(k + 1) & 1][nt] = *reinterpret_cast<const h8*>(wn + laneBv + nt * 256);
            }
            // A-lo just-in-time (consumed as 3rd term per mt)
            h8 Al[4];
            #pragma unroll
            for (int mt = 0; mt < 4; ++mt)
                Al[mt] = *reinterpret_cast<const h8*>(srcCk + AloOff[k] + mt * mtStride);
            const char* bk = sB + k * 4096;
            h8 Bh[4];
            #pragma unroll
            for (int nt = 0; nt < 4; ++nt)
                Bh[nt] = *reinterpret_cast<const h8*>(bk + laneBv + nt * 256);
            #pragma unroll
            for (int mt = 0; mt < 4; ++mt) {
                h8 Ah = *reinterpret_cast<const h8*>(sA + (wv * 4 + mt) * 576 + laneAhi[k]);
                #pragma unroll
                for (int nt = 0; nt < 4; ++nt) {
                    acc[mt][nt] = __builtin_amdgcn_mfma_f32_16x16x32_f16(Ah, Bh[nt], acc[mt][nt], 0, 0, 0);
                    acc[mt][nt] = __builtin_amdgcn_mfma_f32_16x16x32_f16(Ah, Bl[k & 1][nt], acc[mt][nt], 0, 0, 0);
                    acc[mt][nt] = __builtin_amdgcn_mfma_f32_16x16x32_f16(Al[mt], Bh[nt], acc[mt][nt], 0, 0, 0);
                }
            }
        }
        __syncthreads();
    }

    // ---- epilogue: C frag col(n)=laneCol (co), row(m)=g*4+i (4 consec px)
    const int HW = W * W;
    if (epi == 0) {
        char* dstB = bufOut + (size_t)(head * 4 + img) * ACT_SLAB;
        _Float16* eW = reinterpret_cast<_Float16*>(sB + wv * 1024);  // per-wave 1KB
        const int ci8 = laneCol & 7;
        const int hf  = laneCol >> 3;
        const int rpx = lane & 15, rhalf = (lane >> 4) & 1, rplane = lane >> 5;
        const int rOff = rpx * 32 + rplane * 16 + rhalf * 8;
        const int rx = tileX + rpx;
        #pragma unroll
        for (int mt = 0; mt < 4; ++mt) {
            int y = tileY + wv * 4 + mt;
            bool yok = (y < W);
            #pragma unroll
            for (int nt = 0; nt < 4; ++nt) {
                int coG = coBase + nt * 16 + laneCol;
                float b = bsel[coG];
                #pragma unroll
                for (int i = 0; i < 4; ++i) {
                    float v = fmaxf(acc[mt][nt][i] + b, 0.f);
                    _Float16 hh = (_Float16)v;
                    _Float16 ll = (_Float16)(v - (float)hh);
                    int px = g * 4 + i;
                    eW[px * 32 + hf * 8 + ci8] = hh;          // plane 0
                    eW[px * 32 + 16 + hf * 8 + ci8] = ll;     // plane 1
                }
                __syncthreads();
                if (yok && rx < W) {
                    int chunkIdx = (coBase + nt * 16) >> 4;
                    size_t slot = (size_t)chunkIdx * CHUNK_SLOTS + (size_t)rplane * PCHUNK
                                + plvl + (size_t)((y + 1) * 2 + rhalf) * C + (rx + 1);
                    *reinterpret_cast<h8*>(dstB + slot * 16) =
                        *reinterpret_cast<const h8*>(eW + rOff);
                }
                __syncthreads();
            }
        }
    } else if (epi == 1) {
        unsigned* kb = keys + (size_t)img * IMG_KEY + c_keyOff[lvl];
        #pragma unroll
        for (int mt = 0; mt < 4; ++mt) {
            int y = tileY + wv * 4 + mt;
            int x0 = tileX + g * 4;
            if (y >= W || x0 >= W) continue;
            #pragma unroll
            for (int nt = 0; nt < 4; ++nt) {
                int coG = coBase + nt * 16 + laneCol;
                if (coG >= C_out) continue;
                float b = bsel[coG];
                unsigned kq[4];
                #pragma unroll
                for (int i = 0; i < 4; ++i) {
                    float sc = 1.0f / (1.0f + expf(-(acc[mt][nt][i] + b)));
                    kq[i] = (sc > 0.05f) ? __float_as_uint(sc) : 0u;
                }
                *reinterpret_cast<uint4*>(kb + (size_t)coG * HW + y * W + x0) =
                    make_uint4(kq[0], kq[1], kq[2], kq[3]);
            }
        }
    } else {
        float* rb = regb + (size_t)img * IMG_REG + c_regOff[lvl];
        #pragma unroll
        for (int mt = 0; mt < 4; ++mt) {
            int y = tileY + wv * 4 + mt;
            if (y >= W) continue;
            #pragma unroll
            for (int nt = 0; nt < 4; ++nt) {
                int coG = nt * 16 + laneCol;
                if (coG >= C_out) continue;
                float b = bsel[coG];
                int a = coG >> 2, jj = coG & 3;
                #pragma unroll
                for (int i = 0; i < 4; ++i) {
                    int x = tileX + g * 4 + i;
                    if (x >= W) continue;
                    rb[((size_t)(y * W + x) * A_NUM + a) * 4 + jj] = acc[mt][nt][i] + b;
                }
            }
        }
    }
}

// ---------------------------------------------------------------------------
__global__ __launch_bounds__(256) void hist_k(const unsigned* __restrict__ keys,
                                              unsigned* __restrict__ hist)
{
    int il = blockIdx.y, img = il >> 2, lvl = il & 3;
    int n = c_keyCnt[lvl];
    int chunk = blockIdx.x * 16384;
    if (chunk >= n) return;
    __shared__ unsigned h[HBINS];
    for (int t = threadIdx.x; t < HBINS; t += 256) h[t] = 0;
    __syncthreads();
    const uint4* k4 = (const uint4*)(keys + (size_t)img * IMG_KEY + c_keyOff[lvl]);
    int i0 = chunk >> 2, i1 = min(chunk + 16384, n) >> 2;
    for (int i = i0 + (int)threadIdx.x; i < i1; i += 256) {
        uint4 kv = k4[i];
        if (kv.x) atomicAdd(&h[kv.x >> 18], 1u);
        if (kv.y) atomicAdd(&h[kv.y >> 18], 1u);
        if (kv.z) atomicAdd(&h[kv.z >> 18], 1u);
        if (kv.w) atomicAdd(&h[kv.w >> 18], 1u);
    }
    __syncthreads();
    unsigned* gh = hist + (size_t)il * HBINS;
    for (int t = threadIdx.x; t < HBINS; t += 256)
        if (h[t]) atomicAdd(&gh[t], h[t]);
}

__global__ __launch_bounds__(256) void thresh_k(const unsigned* __restrict__ hist,
                                                unsigned* __restrict__ tbin)
{
    const unsigned* h = hist + (size_t)blockIdx.x * HBINS;
    __shared__ unsigned cs[256];
    int tid = threadIdx.x;
    unsigned s = 0;
    int base = tid * 64;
    for (int q = 0; q < 64; ++q) { int b = base + q; if (b >= 1) s += h[b]; }
    cs[tid] = s;
    __syncthreads();
    if (tid == 0) {
        unsigned total = 0, sel = 0;
        for (int c = 255; c >= 0; --c) {
            if (total + cs[c] >= 100u) {
                int lo = (c == 0) ? 1 : c * 64;
                for (int b = c * 64 + 63; b >= lo; --b) {
                    total += h[b];
                    if (total >= 100u) { sel = (unsigned)b; break; }
                }
                break;
            }
            total += cs[c];
        }
        tbin[blockIdx.x] = sel;
    }
}

__global__ __launch_bounds__(256) void compact_k(const unsigned* __restrict__ keys,
                                                 const unsigned* __restrict__ tbin,
                                                 unsigned* __restrict__ cnt,
                                                 uint2* __restrict__ comp)
{
    int il = blockIdx.y, img = il >> 2, lvl = il & 3;
    int n = c_keyCnt[lvl];
    int chunk = blockIdx.x * 16384;
    if (chunk >= n) return;
    const uint4* k4 = (const uint4*)(keys + (size_t)img * IMG_KEY + c_keyOff[lvl]);
    unsigned thr = tbin[il] << 18;
    int shift = 12 - 2 * lvl;
    int hwm = (1 << shift) - 1;
    int i0 = chunk >> 2, i1 = min(chunk + 16384, n) >> 2;
    __shared__ unsigned lcnt, lbase, lcur;
    if (threadIdx.x == 0) { lcnt = 0; lcur = 0; }
    __syncthreads();
    unsigned myc = 0;
    for (int i = i0 + (int)threadIdx.x; i < i1; i += 256) {
        uint4 kv = k4[i];
        myc += (kv.x != 0u && kv.x >= thr);
        myc += (kv.y != 0u && kv.y >= thr);
        myc += (kv.z != 0u && kv.z >= thr);
        myc += (kv.w != 0u && kv.w >= thr);
    }
    if (myc) atomicAdd(&lcnt, myc);
    __syncthreads();
    if (threadIdx.x == 0 && lcnt) lbase = atomicAdd(&cnt[il], lcnt);
    __syncthreads();
    if (lcnt == 0) return;
    uint2* c = comp + (size_t)il * CAP;
    for (int i = i0 + (int)threadIdx.x; i < i1; i += 256) {
        uint4 kv = k4[i];
        unsigned kk[4] = {kv.x, kv.y, kv.z, kv.w};
        #pragma unroll
        for (int j = 0; j < 4; ++j) {
            unsigned key = kk[j];
            if (key != 0u && key >= thr) {
                int t = i * 4 + j;
                int co = t >> shift, p = t & hwm;
                int a = co / NCLS, cls = co - a * NCLS;
                unsigned idx = (unsigned)((p * A_NUM + a) * NCLS + cls);
                unsigned pos = lbase + atomicAdd(&lcur, 1u);
                if (pos < CAP) c[pos] = make_uint2(key, idx);
            }
        }
    }
}

__global__ __launch_bounds__(256) void topsort_k(const unsigned* __restrict__ cnt,
                                                 const uint2* __restrict__ comp,
                                                 uint2* __restrict__ topk)
{
    __shared__ unsigned long long s[CAP];
    int il = blockIdx.x, tid = threadIdx.x;
    int n = (int)min(cnt[il], (unsigned)CAP);
    const uint2* c = comp + (size_t)il * CAP;
    for (int i = tid; i < CAP; i += 256) {
        unsigned long long v = 0ull;
        if (i < n) {
            uint2 e = c[i];
            v = ((unsigned long long)e.x << 32) | (unsigned long long)(~e.y);
        }
        s[i] = v;
    }
    for (int k = 2; k <= CAP; k <<= 1) {
        for (int j = k >> 1; j > 0; j >>= 1) {
            __syncthreads();
            for (int p = tid; p < CAP / 2; p += 256) {
                int i = ((p & ~(j - 1)) << 1) | (p & (j - 1));
                int ixj = i | j;
                unsigned long long a = s[i], b = s[ixj];
                if (((i & k) == 0) ? (a < b) : (a > b)) { s[i] = b; s[ixj] = a; }
            }
        }
    }
    __syncthreads();
    if (tid < 100) {
        unsigned long long v = s[tid];
        topk[il * 100 + tid] = make_uint2((unsigned)(v >> 32), ~(unsigned)(v & 0xFFFFFFFFull));
    }
}

// ---------------------------------------------------------------------------
__global__ void decode_k(const uint2* __restrict__ topk, const float* __restrict__ regb,
                         float* __restrict__ cboxes, float* __restrict__ cscores,
                         int* __restrict__ clabels, const int* __restrict__ ph, const int* __restrict__ pw)
{
    int il = blockIdx.x, img = il >> 2, lvl = il & 3;
    int j = threadIdx.x;
    if (j >= 100) return;
    float imgW = (float)pw[0], imgH = (float)ph[0];
    uint2 tk = topk[il * 100 + j];
    int outP = img * 400 + lvl * 100 + j;
    if (tk.x == 0u) {
        cboxes[outP * 4 + 0] = 0.f; cboxes[outP * 4 + 1] = 0.f;
        cboxes[outP * 4 + 2] = 0.f; cboxes[outP * 4 + 3] = 0.f;
        cscores[outP] = -1.0f; clabels[outP] = -1;
        return;
    }
    float score = __uint_as_float(tk.x);
    unsigned idx = tk.y;
    int aidx = (int)(idx / NCLS);
    int lbl  = (int)(idx - (unsigned)aidx * NCLS);
    int a = aidx % A_NUM, p = aidx / A_NUM;
    int W = c_W[lvl];
    int y = p / W, x = p - y * W;
    int r = a / 3, si = a - r * 3;
    float ratio = (r == 0) ? 0.5f : ((r == 1) ? 1.0f : 2.0f);
    float size = c_sizes[lvl][si];
    float hr = sqrtf(ratio);
    float wr = 1.0f / hr;
    float wsz = wr * size, hsz = hr * size;
    float bw = rintf(wsz * 0.5f), bh = rintf(hsz * 0.5f);
    float sx = (float)(x * c_stride[lvl]), sy = (float)(y * c_stride[lvl]);
    float ax1 = fminf(fmaxf(sx - bw, 0.f), imgW);
    float ay1 = fminf(fmaxf(sy - bh, 0.f), imgH);
    float ax2 = fminf(fmaxf(sx + bw, 0.f), imgW);
    float ay2 = fminf(fmaxf(sy + bh, 0.f), imgH);
    float aw = ax2 - ax1, ah = ay2 - ay1;
    float cx = ax1 + 0.5f * aw, cy = ay1 + 0.5f * ah;
    const float* rel = regb + (size_t)img * IMG_REG + c_regOff[lvl] + (size_t)aidx * 4;
    float dx = rel[0], dy = rel[1];
    float dw = fminf(rel[2], 4.135166556742356f);
    float dh = fminf(rel[3], 4.135166556742356f);
    float pcx = dx * aw + cx, pcy = dy * ah + cy;
    float pwd = expf(dw) * aw, phd = expf(dh) * ah;
    float x1 = pcx - 0.5f * pwd, y1 = pcy - 0.5f * phd;
    float x2 = pcx + 0.5f * pwd, y2 = pcy + 0.5f * phd;
    cboxes[outP * 4 + 0] = fminf(fmaxf(x1, 0.f), imgW);
    cboxes[outP * 4 + 1] = fminf(fmaxf(y1, 0.f), imgH);
    cboxes[outP * 4 + 2] = fminf(fmaxf(x2, 0.f), imgW);
    cboxes[outP * 4 + 3] = fminf(fmaxf(y2, 0.f), imgH);
    cscores[outP] = score;
    clabels[outP] = lbl;
}

__global__ __launch_bounds__(512) void nms_k(const float* __restrict__ cboxes,
                                             const float* __restrict__ cscores,
                                             const int* __restrict__ clabels,
                                             const int* __restrict__ ph, const int* __restrict__ pw,
                                             float* __restrict__ out)
{
    int img = blockIdx.x, tid = threadIdx.x;
    __shared__ float sSc[512];
    __shared__ int   sPos[512];
    __shared__ float bx1[400], by1[400], bx2[400], by2[400], sAr[400];
    __shared__ int   sKeep[400], sLbl[400];
    float imgH = (float)ph[0], imgW = (float)pw[0];
    float offm = fmaxf(imgH, imgW) + 1.0f;

    sSc[tid] = (tid < 400) ? cscores[img * 400 + tid] : -3.0f;
    sPos[tid] = tid;
    __syncthreads();

    for (int k = 2; k <= 512; k <<= 1) {
        for (int jj = k >> 1; jj > 0; jj >>= 1) {
            int ixj = tid ^ jj;
            if (ixj > tid) {
                float s1 = sSc[tid], s2 = sSc[ixj];
                int p1 = sPos[tid], p2 = sPos[ixj];
                bool bef = (s1 > s2) || (s1 == s2 && p1 < p2);
                bool sw = ((tid & k) == 0) ? (!bef) : bef;
                if (sw) { sSc[tid] = s2; sSc[ixj] = s1; sPos[tid] = p2; sPos[ixj] = p1; }
            }
            __syncthreads();
        }
    }

    if (tid < 400) {
        int p = sPos[tid];
        int lbl = clabels[img * 400 + p];
        float ofs = (float)lbl * offm;
        float x1 = cboxes[(img * 400 + p) * 4 + 0] + ofs;
        float y1 = cboxes[(img * 400 + p) * 4 + 1] + ofs;
        float x2 = cboxes[(img * 400 + p) * 4 + 2] + ofs;
        float y2 = cboxes[(img * 400 + p) * 4 + 3] + ofs;
        bx1[tid] = x1; by1[tid] = y1; bx2[tid] = x2; by2[tid] = y2;
        sAr[tid] = (x2 - x1) * (y2 - y1);
        sLbl[tid] = lbl;
        sKeep[tid] = (sSc[tid] > 0.05f) ? 1 : 0;
    }
    __syncthreads();

    for (int i = 0; i < 400; ++i) {
        if (sKeep[i]) {
            for (int j2 = i + 1 + tid; j2 < 400; j2 += 512) {
                float ltx = fmaxf(bx1[i], bx1[j2]), lty = fmaxf(by1[i], by1[j2]);
                float rbx = fminf(bx2[i], bx2[j2]), rby = fminf(by2[i], by2[j2]);
                float ww = fmaxf(rbx - ltx, 0.f), hh = fmaxf(rby - lty, 0.f);
                float inter = ww * hh;
                float iou = inter / (((sAr[i] + sAr[j2]) - inter) + 1e-9f);
                if (iou > 0.5f) sKeep[j2] = 0;
            }
        }
        __syncthreads();
    }

    if (tid == 0) {
        int rank = 0;
        for (int i = 0; i < 400 && rank < 100; ++i) {
            if (sKeep[i]) {
                int p = sPos[i];
                for (int kk = 0; kk < 4; ++kk)
                    out[(img * 100 + rank) * 4 + kk] = cboxes[(img * 400 + p) * 4 + kk];
                out[1600 + img * 100 + rank] = sSc[i];
                out[2000 + img * 100 + rank] = (float)sLbl[i];
                ++rank;
            }
        }
        for (; rank < 100; ++rank) {
            for (int kk = 0; kk < 4; ++kk) out[(img * 100 + rank) * 4 + kk] = 0.f;
            out[1600 + img * 100 + rank] = 0.f;
            out[2000 + img * 100 + rank] = -1.0f;
        }
    }
}

// ---------------------------------------------------------------------------
extern "C" void kernel_launch(void* const* d_in, const int* in_sizes, int n_in,
                              void* d_out, int out_size, void* d_ws, size_t ws_size,
                              hipStream_t stream)
{
    const float* f0 = (const float*)d_in[0];
    const float* f1 = (const float*)d_in[1];
    const float* f2 = (const float*)d_in[2];
    const float* f3 = (const float*)d_in[3];
    const float* cls_tw = (const float*)d_in[4];
    const float* cls_tb = (const float*)d_in[5];
    const float* cls_ow = (const float*)d_in[6];
    const float* cls_ob = (const float*)d_in[7];
    const float* reg_tw = (const float*)d_in[8];
    const float* reg_tb = (const float*)d_in[9];
    const float* reg_ow = (const float*)d_in[10];
    const float* reg_ob = (const float*)d_in[11];
    const int* ph = (const int*)d_in[12];
    const int* pw = (const int*)d_in[13];
    float* out = (float*)d_out;

    char* ws = (char*)d_ws;
    size_t off = 0;
    auto alloc = [&](size_t bytes) -> void* {
        void* p = ws + off;
        off = (off + bytes + 1023) & ~(size_t)1023;
        return p;
    };
    const size_t KEYS = (size_t)4 * IMG_KEY * 4;    // 62.7 MB
    const size_t ACT8 = ACT_SLAB * 8;               // 49.3 MB (8 img-head slabs)
    // +32KB slack: lvl3 16-row staging/lo reads overrun chunk/slab ends (discarded)
    char*     Pin    = (char*)alloc(ACT_SLAB * 4 + 32768);
    char*     slabA  = (char*)alloc((KEYS > ACT8 ? KEYS : ACT8) + 32768);
    unsigned* keys   = (unsigned*)slabA;
    char*     actA   = slabA;
    char*     actB   = (char*)alloc(ACT8 + 32768);
    u16*      repCT  = (u16*)alloc((size_t)16 * WCOG_BYTES);   // 4 layers * 4 cg
    u16*      repRT  = (u16*)alloc((size_t)16 * WCOG_BYTES);
    u16*      repCO  = (u16*)alloc((size_t)12 * WCOG_BYTES);   // 12 cg
    u16*      repRO  = (u16*)alloc((size_t)1 * WCOG_BYTES);
    float*    regb   = (float*)alloc((size_t)4 * IMG_REG * 4);
    unsigned* hist   = (unsigned*)alloc((size_t)16 * HBINS * 4);
    unsigned* cnt    = (unsigned*)alloc(16 * 4);
    unsigned* tbin   = (unsigned*)alloc(16 * 4);
    uint2*    comp   = (uint2*)alloc((size_t)16 * CAP * 8);
    uint2*    topk   = (uint2*)alloc((size_t)1600 * 8);
    float*    cboxes = (float*)alloc((size_t)4 * 400 * 4 * 4);
    float*    cscores= (float*)alloc((size_t)4 * 400 * 4);
    int*      clabels= (int*)alloc((size_t)4 * 400 * 4);

    // zero halos (act slabs must be re-zeroed each launch) + accumulators
    hipMemsetAsync(Pin, 0, ACT_SLAB * 4, stream);
    hipMemsetAsync(actA, 0, ACT8, stream);
    hipMemsetAsync(actB, 0, ACT8, stream);
    hipMemsetAsync(hist, 0, (size_t)16 * HBINS * 4, stream);
    hipMemsetAsync(cnt, 0, 64, stream);

    // prep: pad inputs (plane-major f16 hi/lo), repack weights
    {
        int tPad = 4 * 16 * 2 * 1360;
        pad16_k<<<(tPad + 255) / 256, 256, 0, stream>>>(f0, f1, f2, f3, Pin);
        int tT = 4 * 4 * 16 * 1280;
        repack16_k<<<(tT + 255) / 256, 256, 0, stream>>>(cls_tw, repCT, 256, 4, tT);
        repack16_k<<<(tT + 255) / 256, 256, 0, stream>>>(reg_tw, repRT, 256, 4, tT);
        int tCO = 12 * 16 * 1280;
        repack16_k<<<(tCO + 255) / 256, 256, 0, stream>>>(cls_ow, repCO, 720, 12, tCO);
        int tRO = 16 * 1280;
        repack16_k<<<(tRO + 255) / 256, 256, 0, stream>>>(reg_ow, repRO, 36, 1, tRO);
    }

    const size_t RL = (size_t)4 * 16 * 20480;   // per-layer repack stride (u16 elems)
    // tower: L0 Pin->A, L1 A->B, L2 B->A, L3 A->B  (1-D grid, XCD-remapped)
    conv16<<<704, 256, 0, stream>>>(Pin, Pin, actA,
        repCT, cls_tb, repRT, reg_tb, keys, regb, 0, 1);
    conv16<<<704, 256, 0, stream>>>(Pin, actA, actB,
        repCT + RL, cls_tb + 256, repRT + RL, reg_tb + 256, keys, regb, 0, 0);
    conv16<<<704, 256, 0, stream>>>(Pin, actB, actA,
        repCT + 2 * RL, cls_tb + 512, repRT + 2 * RL, reg_tb + 512, keys, regb, 0, 0);
    conv16<<<704, 256, 0, stream>>>(Pin, actA, actB,
        repCT + 3 * RL, cls_tb + 768, repRT + 3 * RL, reg_tb + 768, keys, regb, 0, 0);
    // out-convs: read B, write keys(=slabA, free now) + regb
    conv16<<<1144, 256, 0, stream>>>(Pin, actB, nullptr,
        repCO, cls_ob, repRO, reg_ob, keys, regb, 1, 0);

    hist_k<<<dim3(180, 16), 256, 0, stream>>>(keys, hist);
    thresh_k<<<16, 256, 0, stream>>>(hist, tbin);
    compact_k<<<dim3(180, 16), 256, 0, stream>>>(keys, tbin, cnt, comp);
    topsort_k<<<16, 256, 0, stream>>>(cnt, comp, topk);
    decode_k<<<16, 128, 0, stream>>>(topk, regb, cboxes, cscores, clabels, ph, pw);
    nms_k<<<4, 512, 0, stream>>>(cboxes, cscores, clabels, ph, pw, out);
}